// Round 13
// baseline (798.460 us; speedup 1.0000x reference)
//
#include <hip/hip_runtime.h>
#include <hip/hip_bf16.h>

static constexpr int Bn = 8, Dn = 512, Hn = 64, Wn = 64, Kn = 1024;
static constexpr int HW = Hn * Wn;            // 4096
static constexpr int NPIX = Bn * HW;          // 32768
static constexpr size_t OFF_LOSS = (size_t)Bn * Dn * HW;          // 16777216
static constexpr size_t OFF_PROB = OFF_LOSS + 1;                   // 16777217
static constexpr size_t OFF_IDX  = OFF_PROB + (size_t)NPIX * Kn;   // 50331649
static constexpr size_t OFF_PPRB = OFF_IDX + NPIX;                 // 50364417

typedef __attribute__((ext_vector_type(8))) short short8v;
typedef __attribute__((ext_vector_type(4))) float f32x4;
typedef unsigned long long ull;

// workspace layout (bytes)
static constexpr size_t WS_CB2   = 0;         // 1024 f32
static constexpr size_t WS_XXZ   = 4096;      // 32768 f32
static constexpr size_t WS_WIDX  = 135168;    // 32768 i32
static constexpr size_t WS_PART  = 266240;    // 4096 f32
static constexpr size_t WS_CBBF  = 282624;    // 1024*512 bf16 (1 MB)
static constexpr size_t WS_ABF   = 1331200;   // optional 64 MiB A-bf16 scratch
static constexpr size_t ABF_BYTES = (size_t)2 * NPIX * Dn * 2;  // 67108864

#define MARGIN 1e-3f
#define CAP 192

__device__ inline unsigned short f2bf(float x) {
  unsigned u = __float_as_uint(x);
  u += 0x7fffu + ((u >> 16) & 1u);  // RNE
  return (unsigned short)(u >> 16);
}
__device__ inline unsigned pack2(float a, float b) {
  return (unsigned)f2bf(a) | ((unsigned)f2bf(b) << 16);
}

__device__ inline void gload_lds16(const void* g, void* l) {
  __builtin_amdgcn_global_load_lds((const __attribute__((address_space(1))) void*)g,
                                   (__attribute__((address_space(3))) void*)l, 16, 0, 0);
}

// ---- numpy pairwise-sum replica for n=512 f32 row of squares ----
__device__ float np_pairwise_sq512(const float* __restrict__ base, int stride) {
  float B[4];
#pragma unroll
  for (int blk = 0; blk < 4; blk++) {
    const float* a = base + (size_t)blk * 128 * stride;
    float r[8][4];
#pragma unroll
    for (int k = 0; k < 8; k++)
#pragma unroll
      for (int j = 0; j < 4; j++) {
        float x = a[(size_t)(4 * k + j) * stride];
        r[k][j] = __fmul_rn(x, x);
      }
#pragma unroll
    for (int i = 32; i < 128; i += 32)
#pragma unroll
      for (int k = 0; k < 8; k++)
#pragma unroll
        for (int j = 0; j < 4; j++) {
          float x = a[(size_t)(i + 4 * k + j) * stride];
          r[k][j] = __fadd_rn(r[k][j], __fmul_rn(x, x));
        }
    float L[4];
#pragma unroll
    for (int j = 0; j < 4; j++) {
      float t01 = __fadd_rn(r[0][j], r[1][j]);
      float t23 = __fadd_rn(r[2][j], r[3][j]);
      float t45 = __fadd_rn(r[4][j], r[5][j]);
      float t67 = __fadd_rn(r[6][j], r[7][j]);
      L[j] = __fadd_rn(__fadd_rn(t01, t23), __fadd_rn(t45, t67));
    }
    B[blk] = __fadd_rn(__fadd_rn(L[0], L[1]), __fadd_rn(L[2], L[3]));
  }
  return __fadd_rn(__fadd_rn(B[0], B[1]), __fadd_rn(B[2], B[3]));
}

// ---------------- K0: CB->bf16, A transpose->bf16 scratch, norms ----------
__global__ __launch_bounds__(256) void k_init(const float* __restrict__ Z,
                                              const float* __restrict__ ZP,
                                              const float* __restrict__ CB,
                                              unsigned short* __restrict__ CBbf,
                                              unsigned short* __restrict__ Abf,
                                              float* __restrict__ xxZ,
                                              float* __restrict__ cb2) {
  int gid = blockIdx.x * 256 + threadIdx.x;
  {
    float2 f = *(const float2*)(CB + (size_t)gid * 2);
    union { __hip_bfloat162 h; unsigned u; } cv;
    cv.h = __float22bfloat162_rn(f);
    ((unsigned*)CBbf)[gid] = cv.u;
  }
  if (gid < 2 * NPIX) {
    const int p = gid & (NPIX - 1);
    const bool isz = gid < NPIX;
    const float* src = (isz ? Z : ZP) + (size_t)(p >> 12) * (Dn * HW) + (p & 4095);
    unsigned short* dst = Abf + (size_t)gid * Dn;
    float Bb[4];
#pragma unroll
    for (int blk = 0; blk < 4; blk++) {
      float rr[32];
#pragma unroll
      for (int i = 0; i < 128; i += 32) {
        float v[32];
#pragma unroll
        for (int t = 0; t < 32; t++) v[t] = src[(size_t)(blk * 128 + i + t) * HW];
        uint4 ua;
        unsigned* uw = (unsigned*)&ua;
#pragma unroll
        for (int q = 0; q < 4; q++) {
#pragma unroll
          for (int e = 0; e < 4; e++) uw[e] = pack2(v[q * 8 + 2 * e], v[q * 8 + 2 * e + 1]);
          *(uint4*)&dst[blk * 128 + i + q * 8] = ua;
        }
        if (isz) {
          if (i == 0) {
#pragma unroll
            for (int t = 0; t < 32; t++) rr[t] = __fmul_rn(v[t], v[t]);
          } else {
#pragma unroll
            for (int t = 0; t < 32; t++) rr[t] = __fadd_rn(rr[t], __fmul_rn(v[t], v[t]));
          }
        }
      }
      if (isz) {
        float L[4];
#pragma unroll
        for (int j = 0; j < 4; j++) {
          float t01 = __fadd_rn(rr[0 + j], rr[4 + j]);
          float t23 = __fadd_rn(rr[8 + j], rr[12 + j]);
          float t45 = __fadd_rn(rr[16 + j], rr[20 + j]);
          float t67 = __fadd_rn(rr[24 + j], rr[28 + j]);
          L[j] = __fadd_rn(__fadd_rn(t01, t23), __fadd_rn(t45, t67));
        }
        Bb[blk] = __fadd_rn(__fadd_rn(L[0], L[1]), __fadd_rn(L[2], L[3]));
      }
    }
    if (isz)
      xxZ[p] = __fadd_rn(__fadd_rn(Bb[0], Bb[1]), __fadd_rn(Bb[2], Bb[3]));
  } else if (gid < 2 * NPIX + Kn) {
    int k = gid - 2 * NPIX;
    cb2[k] = np_pairwise_sq512(CB + (size_t)k * Dn, 1);
  }
}

// ---------------- K1: 2-pass fused GEMM: stats then probs (no s matrix) ----
// grid 1024 (= 512 p-blocks x 2 mats), block 256 (4 waves, 2m x 2n).
// Block: 64 pixels x full K=1024, kx-loop of 8 tiles (round-12 inner loop).
// Pass 1: per-row (v1,i1,v2,sum) only. Pass 2: bit-identical recompute ->
// probs written directly + in-margin candidates listed; then exact refine.
__global__ __launch_bounds__(256) void k_fused(const unsigned short* __restrict__ Abf,
                                               const unsigned short* __restrict__ CBbf,
                                               const float* __restrict__ CB,
                                               const float* __restrict__ Z,
                                               const float* __restrict__ cb2,
                                               const float* __restrict__ xxZ,
                                               float* __restrict__ out,
                                               int* __restrict__ widx) {
  __shared__ __align__(16) unsigned short At[2][64 * 32];    // 4 KB each
  __shared__ __align__(16) unsigned short Bt[2][128 * 32];   // 8 KB each
  __shared__ float rs_v1[2][64];
  __shared__ int   rs_i1[2][64];
  __shared__ float rs_v2[2][64];
  __shared__ float rs_sum[2][64];
  __shared__ float rf_thr[64];
  __shared__ float rf_inv[64];
  __shared__ int   rf_i1[64];
  __shared__ int   clist[CAP];
  __shared__ float rd_d[CAP];
  __shared__ int   cnt;

  const int bid = blockIdx.x;
  const int zz = bid & 1;
  const int py = bid >> 1;
  const int p0 = py * 64;
  const unsigned short* Asrc = Abf + (size_t)(zz * NPIX + p0) * Dn;
  float* S = out + (zz ? OFF_PPRB : OFF_PROB);

  const int tid = threadIdx.x;
  const int lane = tid & 63, w = tid >> 6;
  const int fr = lane & 15, fg = lane >> 4;
  const int wm = w & 1, wn = w >> 1;
  const int swz = (fr >> 1) & 3;
  if (tid == 0) cnt = 0;

  auto stage = [&](int buf, int t) {
    const int c0 = (t & 15) * 32;
    const int k0 = (t >> 4) * 128;
    {  // A: 64 rows x 32 c
      const int row = tid >> 2, g = tid & 3;
      const int gsrc = g ^ ((row >> 1) & 3);
      const int ldsbase = (tid & 192) * 8;  // wave-uniform
      gload_lds16(Asrc + (size_t)row * Dn + c0 + gsrc * 8, &At[buf][ldsbase]);
    }
#pragma unroll
    for (int h = 0; h < 2; h++) {  // B: 128 rows x 32 c
      const int G = tid + h * 256;
      const int row = G >> 2, g = G & 3;
      const int gsrc = g ^ ((row >> 1) & 3);
      const int ldsbase = ((tid & 192) + h * 256) * 8;  // wave-uniform
      gload_lds16(CBbf + (size_t)(k0 + row) * Dn + c0 + gsrc * 8, &Bt[buf][ldsbase]);
    }
  };

  // ================= pass 1: stats =================
  {
    float v1a[8], v2a[8], suma[8];
    int i1a[8];
#pragma unroll
    for (int q = 0; q < 8; q++) {
      v1a[q] = 1e30f; v2a[q] = 1e30f; suma[q] = 0.f; i1a[q] = 0x7fffffff;
    }
    stage(0, 0);
    int t = 0;
    for (int kx = 0; kx < 8; kx++) {
      const int k0 = kx * 128;
      f32x4 acc[2][4] = {};
#pragma unroll
      for (int s = 0; s < 16; s++, t++) {
        __syncthreads();
        if (t < 127) stage((t + 1) & 1, t + 1);
        const int cur = t & 1;
        short8v af[2], bf[4];
#pragma unroll
        for (int m = 0; m < 2; m++)
          af[m] = *(const short8v*)&At[cur][(wm * 32 + m * 16 + fr) * 32 + ((fg ^ swz) * 8)];
#pragma unroll
        for (int n = 0; n < 4; n++)
          bf[n] = *(const short8v*)&Bt[cur][(wn * 64 + n * 16 + fr) * 32 + ((fg ^ swz) * 8)];
#pragma unroll
        for (int m = 0; m < 2; m++)
#pragma unroll
          for (int n = 0; n < 4; n++)
            acc[m][n] = __builtin_amdgcn_mfma_f32_16x16x32_bf16(af[m], bf[n], acc[m][n], 0, 0, 0);
      }
      float c2t[4];
#pragma unroll
      for (int n = 0; n < 4; n++) c2t[n] = cb2[k0 + wn * 64 + n * 16 + fr];
#pragma unroll
      for (int m = 0; m < 2; m++)
#pragma unroll
        for (int r = 0; r < 4; r++) {
          const int slot = m * 4 + r;
#pragma unroll
          for (int n = 0; n < 4; n++) {
            float sv = __fsub_rn(c2t[n], __fmul_rn(2.0f, acc[m][n][r]));
            int k = k0 + wn * 64 + n * 16 + fr;
            suma[slot] += __expf(-sv);
            if (sv < v1a[slot]) { v2a[slot] = v1a[slot]; v1a[slot] = sv; i1a[slot] = k; }
            else if (sv < v2a[slot]) v2a[slot] = sv;
          }
        }
    }
    // merge over fr (butterfly) then over wn (LDS)
#pragma unroll
    for (int m = 0; m < 2; m++)
#pragma unroll
      for (int r = 0; r < 4; r++) {
        const int slot = m * 4 + r;
        float v1 = v1a[slot], v2 = v2a[slot], sm = suma[slot];
        int i1 = i1a[slot];
#pragma unroll
        for (int d = 1; d < 16; d <<= 1) {
          float ov1 = __shfl_xor(v1, d, 64);
          int oi1 = __shfl_xor(i1, d, 64);
          float ov2 = __shfl_xor(v2, d, 64);
          float os = __shfl_xor(sm, d, 64);
          sm += os;
          float lose;
          if (ov1 < v1 || (ov1 == v1 && oi1 < i1)) { lose = v1; v1 = ov1; i1 = oi1; }
          else lose = ov1;
          v2 = fminf(fminf(v2, ov2), lose);
        }
        if (fr == 0) {
          const int row = wm * 32 + m * 16 + fg * 4 + r;
          rs_v1[wn][row] = v1; rs_i1[wn][row] = i1;
          rs_v2[wn][row] = v2; rs_sum[wn][row] = sm;
        }
      }
    __syncthreads();
    if (tid < 64) {
      float v1 = rs_v1[0][tid]; int i1 = rs_i1[0][tid];
      float v2 = rs_v2[0][tid]; float sm = rs_sum[0][tid];
      float ov1 = rs_v1[1][tid]; int oi1 = rs_i1[1][tid];
      float ov2 = rs_v2[1][tid];
      sm += rs_sum[1][tid];
      float lose;
      if (ov1 < v1 || (ov1 == v1 && oi1 < i1)) { lose = v1; v1 = ov1; i1 = oi1; }
      else lose = ov1;
      v2 = fminf(fminf(v2, ov2), lose);
      rf_inv[tid] = 1.0f / sm;
      rf_i1[tid] = i1;
      rf_thr[tid] = (zz == 0 && v2 <= v1 + MARGIN) ? (v1 + MARGIN) : -1e30f;
    }
    __syncthreads();
  }

  // ================= pass 2: probs + candidate collect =================
  {
    float thr8[8], inv8[8];
#pragma unroll
    for (int m = 0; m < 2; m++)
#pragma unroll
      for (int r = 0; r < 4; r++) {
        const int row = wm * 32 + m * 16 + fg * 4 + r;
        thr8[m * 4 + r] = rf_thr[row];
        inv8[m * 4 + r] = rf_inv[row];
      }
    stage(0, 0);
    int t = 0;
    for (int kx = 0; kx < 8; kx++) {
      const int k0 = kx * 128;
      f32x4 acc[2][4] = {};
#pragma unroll
      for (int s = 0; s < 16; s++, t++) {
        __syncthreads();
        if (t < 127) stage((t + 1) & 1, t + 1);
        const int cur = t & 1;
        short8v af[2], bf[4];
#pragma unroll
        for (int m = 0; m < 2; m++)
          af[m] = *(const short8v*)&At[cur][(wm * 32 + m * 16 + fr) * 32 + ((fg ^ swz) * 8)];
#pragma unroll
        for (int n = 0; n < 4; n++)
          bf[n] = *(const short8v*)&Bt[cur][(wn * 64 + n * 16 + fr) * 32 + ((fg ^ swz) * 8)];
#pragma unroll
        for (int m = 0; m < 2; m++)
#pragma unroll
          for (int n = 0; n < 4; n++)
            acc[m][n] = __builtin_amdgcn_mfma_f32_16x16x32_bf16(af[m], bf[n], acc[m][n], 0, 0, 0);
      }
      float c2t[4];
#pragma unroll
      for (int n = 0; n < 4; n++) c2t[n] = cb2[k0 + wn * 64 + n * 16 + fr];
#pragma unroll
      for (int m = 0; m < 2; m++)
#pragma unroll
        for (int r = 0; r < 4; r++) {
          const int slot = m * 4 + r;
          const int row = wm * 32 + m * 16 + fg * 4 + r;
          float* Sp = S + (size_t)(p0 + row) * Kn + k0 + wn * 64 + fr;
#pragma unroll
          for (int n = 0; n < 4; n++) {
            float sv = __fsub_rn(c2t[n], __fmul_rn(2.0f, acc[m][n][r]));
            Sp[n * 16] = __expf(-sv) * inv8[slot];
            if (sv <= thr8[slot]) {
              int pos = atomicAdd(&cnt, 1);
              if (pos < CAP) clist[pos] = (row << 10) | (k0 + wn * 64 + n * 16 + fr);
            }
          }
        }
    }
  }
  __syncthreads();

  // ================= refine + final argmin write (z only) =================
  if (zz == 0) {
    const int nc = min(cnt, CAP);
    for (int i = w; i < nc; i += 4) {   // one wave per pair
      const int rowk = clist[i];
      const int row = rowk >> 10, k = rowk & 1023;
      const int p = p0 + row;
      const float* zcol = Z + (size_t)(p >> 12) * (Dn * HW) + (p & 4095);
      const float* cr = CB + (size_t)k * Dn;
      float part = 0.f;
#pragma unroll
      for (int q = 0; q < 8; q++)
        part = fmaf(zcol[(size_t)(lane + 64 * q) * HW], cr[lane + 64 * q], part);
#pragma unroll
      for (int d = 1; d < 64; d <<= 1) part += __shfl_xor(part, d, 64);
      if (lane == 0)
        rd_d[i] = __fsub_rn(__fadd_rn(xxZ[p], cb2[k]), __fmul_rn(2.0f, part));
    }
    __syncthreads();
    if (tid < 64) {
      int fin = rf_i1[tid];
      float bd = 1e30f;
      int bi = 0x7fffffff;
      for (int i = 0; i < nc; i++) {
        if ((clist[i] >> 10) == tid) {
          float dd = rd_d[i];
          int kk = clist[i] & 1023;
          if (dd < bd || (dd == bd && kk < bi)) { bd = dd; bi = kk; }
        }
      }
      if (bi != 0x7fffffff) fin = bi;
      widx[p0 + tid] = fin;
      out[OFF_IDX + p0 + tid] = (float)fin;
    }
  }
}

// ---------------- K2: z_q gather + squared-error partials ----------------
__global__ __launch_bounds__(256) void k_zqloss(const float* __restrict__ Z,
                                                const float* __restrict__ CB,
                                                const int* __restrict__ widx,
                                                float* __restrict__ out,
                                                float* __restrict__ partial) {
  __shared__ float red[256];
  const int t = threadIdx.x;
  float ls = 0.f;
  const size_t base = (size_t)blockIdx.x * 4096;
#pragma unroll
  for (int i = 0; i < 16; i++) {
    size_t e = base + (size_t)i * 256 + t;
    int hw = (int)(e & 4095);
    int c = (int)((e >> 12) & 511);
    int bb = (int)(e >> 21);
    int p = (bb << 12) | hw;
    float zv = Z[e];
    float qv = CB[(size_t)widx[p] * Dn + c];
    out[e] = qv;
    float d = zv - qv;
    ls = fmaf(d, d, ls);
  }
  red[t] = ls;
  __syncthreads();
  for (int s = 128; s > 0; s >>= 1) {
    if (t < s) red[t] += red[t + s];
    __syncthreads();
  }
  if (t == 0) partial[blockIdx.x] = red[0];
}

// ---------------- K3: finalize q_loss ----------------
__global__ __launch_bounds__(256) void k_loss(const float* __restrict__ partial,
                                              float* __restrict__ out) {
  __shared__ float red[256];
  const int t = threadIdx.x;
  float s = 0.f;
  for (int i = t; i < 4096; i += 256) s += partial[i];
  red[t] = s;
  __syncthreads();
  for (int k = 128; k > 0; k >>= 1) {
    if (t < k) red[t] += red[t + k];
    __syncthreads();
  }
  if (t == 0) out[OFF_LOSS] = red[0] * (1.25f / 16777216.0f);
}

extern "C" void kernel_launch(void* const* d_in, const int* in_sizes, int n_in,
                              void* d_out, int out_size, void* d_ws, size_t ws_size,
                              hipStream_t stream) {
  const float* Z = (const float*)d_in[0];
  const float* ZP = (const float*)d_in[1];
  const float* CB = (const float*)d_in[2];
  float* out = (float*)d_out;
  char* ws = (char*)d_ws;
  float* cb2 = (float*)(ws + WS_CB2);
  float* xxZ = (float*)(ws + WS_XXZ);
  int* widx = (int*)(ws + WS_WIDX);
  float* partial = (float*)(ws + WS_PART);
  unsigned short* CBbf = (unsigned short*)(ws + WS_CBBF);
  unsigned short* Abf = (ws_size >= WS_ABF + ABF_BYTES)
                            ? (unsigned short*)(ws + WS_ABF)
                            : (unsigned short*)d_out;

  k_init<<<dim3(1024), 256, 0, stream>>>(Z, ZP, CB, CBbf, Abf, xxZ, cb2);
  k_fused<<<dim3(1024), 256, 0, stream>>>(Abf, CBbf, CB, Z, cb2, xxZ, out, widx);
  k_zqloss<<<dim3(4096), 256, 0, stream>>>(Z, CB, widx, out, partial);
  k_loss<<<dim3(1), 256, 0, stream>>>(partial, out);
}

// Round 14
// 460.985 us; speedup vs baseline: 1.7321x; 1.7321x over previous
//
#include <hip/hip_runtime.h>
#include <hip/hip_bf16.h>

static constexpr int Bn = 8, Dn = 512, Hn = 64, Wn = 64, Kn = 1024;
static constexpr int HW = Hn * Wn;            // 4096
static constexpr int NPIX = Bn * HW;          // 32768
static constexpr size_t OFF_LOSS = (size_t)Bn * Dn * HW;          // 16777216
static constexpr size_t OFF_PROB = OFF_LOSS + 1;                   // 16777217
static constexpr size_t OFF_IDX  = OFF_PROB + (size_t)NPIX * Kn;   // 50331649
static constexpr size_t OFF_PPRB = OFF_IDX + NPIX;                 // 50364417

typedef __attribute__((ext_vector_type(8))) short short8v;
typedef __attribute__((ext_vector_type(4))) float f32x4;
typedef unsigned long long ull;
typedef unsigned int uint32;

// workspace layout (bytes)
static constexpr size_t WS_CB2   = 0;         // 1024 f32
static constexpr size_t WS_XXZ   = 4096;      // 32768 f32
static constexpr size_t WS_WIDX  = 135168;    // 32768 i32
static constexpr size_t WS_PART  = 266240;    // 2048 f32
static constexpr size_t WS_CBBF  = 282624;    // 1024*512 bf16 (1 MB)
static constexpr size_t WS_ABF   = 1331200;   // optional 64 MiB A-bf16 scratch
static constexpr size_t ABF_BYTES = (size_t)2 * NPIX * Dn * 2;  // 67108864

#define MARGIN 6e-3f   // covers bf16-s quantization (<=2.05e-3) + GEMM err

__device__ inline unsigned short f2bf(float x) {
  unsigned u = __float_as_uint(x);
  u += 0x7fffu + ((u >> 16) & 1u);  // RNE
  return (unsigned short)(u >> 16);
}
__device__ inline unsigned pack2(float a, float b) {
  return (unsigned)f2bf(a) | ((unsigned)f2bf(b) << 16);
}
__device__ inline float bf2f(unsigned short h) {
  return __uint_as_float(((unsigned)h) << 16);
}

__device__ inline void gload_lds16(const void* g, void* l) {
  __builtin_amdgcn_global_load_lds((const __attribute__((address_space(1))) void*)g,
                                   (__attribute__((address_space(3))) void*)l, 16, 0, 0);
}

// ---- numpy pairwise-sum replica for n=512 f32 row of squares ----
__device__ float np_pairwise_sq512(const float* __restrict__ base, int stride) {
  float B[4];
#pragma unroll
  for (int blk = 0; blk < 4; blk++) {
    const float* a = base + (size_t)blk * 128 * stride;
    float r[8][4];
#pragma unroll
    for (int k = 0; k < 8; k++)
#pragma unroll
      for (int j = 0; j < 4; j++) {
        float x = a[(size_t)(4 * k + j) * stride];
        r[k][j] = __fmul_rn(x, x);
      }
#pragma unroll
    for (int i = 32; i < 128; i += 32)
#pragma unroll
      for (int k = 0; k < 8; k++)
#pragma unroll
        for (int j = 0; j < 4; j++) {
          float x = a[(size_t)(i + 4 * k + j) * stride];
          r[k][j] = __fadd_rn(r[k][j], __fmul_rn(x, x));
        }
    float L[4];
#pragma unroll
    for (int j = 0; j < 4; j++) {
      float t01 = __fadd_rn(r[0][j], r[1][j]);
      float t23 = __fadd_rn(r[2][j], r[3][j]);
      float t45 = __fadd_rn(r[4][j], r[5][j]);
      float t67 = __fadd_rn(r[6][j], r[7][j]);
      L[j] = __fadd_rn(__fadd_rn(t01, t23), __fadd_rn(t45, t67));
    }
    B[blk] = __fadd_rn(__fadd_rn(L[0], L[1]), __fadd_rn(L[2], L[3]));
  }
  return __fadd_rn(__fadd_rn(B[0], B[1]), __fadd_rn(B[2], B[3]));
}

// ---------------- K0: CB->bf16, A transpose->bf16 scratch, norms ----------
__global__ __launch_bounds__(256) void k_init(const float* __restrict__ Z,
                                              const float* __restrict__ ZP,
                                              const float* __restrict__ CB,
                                              unsigned short* __restrict__ CBbf,
                                              unsigned short* __restrict__ Abf,
                                              float* __restrict__ xxZ,
                                              float* __restrict__ cb2) {
  int gid = blockIdx.x * 256 + threadIdx.x;
  {
    float2 f = *(const float2*)(CB + (size_t)gid * 2);
    union { __hip_bfloat162 h; unsigned u; } cv;
    cv.h = __float22bfloat162_rn(f);
    ((unsigned*)CBbf)[gid] = cv.u;
  }
  if (gid < 2 * NPIX) {
    const int p = gid & (NPIX - 1);
    const bool isz = gid < NPIX;
    const float* src = (isz ? Z : ZP) + (size_t)(p >> 12) * (Dn * HW) + (p & 4095);
    unsigned short* dst = Abf + (size_t)gid * Dn;
    float Bb[4];
#pragma unroll
    for (int blk = 0; blk < 4; blk++) {
      float rr[32];
#pragma unroll
      for (int i = 0; i < 128; i += 32) {
        float v[32];
#pragma unroll
        for (int t = 0; t < 32; t++) v[t] = src[(size_t)(blk * 128 + i + t) * HW];
        uint4 ua;
        unsigned* uw = (unsigned*)&ua;
#pragma unroll
        for (int q = 0; q < 4; q++) {
#pragma unroll
          for (int e = 0; e < 4; e++) uw[e] = pack2(v[q * 8 + 2 * e], v[q * 8 + 2 * e + 1]);
          *(uint4*)&dst[blk * 128 + i + q * 8] = ua;
        }
        if (isz) {
          if (i == 0) {
#pragma unroll
            for (int t = 0; t < 32; t++) rr[t] = __fmul_rn(v[t], v[t]);
          } else {
#pragma unroll
            for (int t = 0; t < 32; t++) rr[t] = __fadd_rn(rr[t], __fmul_rn(v[t], v[t]));
          }
        }
      }
      if (isz) {
        float L[4];
#pragma unroll
        for (int j = 0; j < 4; j++) {
          float t01 = __fadd_rn(rr[0 + j], rr[4 + j]);
          float t23 = __fadd_rn(rr[8 + j], rr[12 + j]);
          float t45 = __fadd_rn(rr[16 + j], rr[20 + j]);
          float t67 = __fadd_rn(rr[24 + j], rr[28 + j]);
          L[j] = __fadd_rn(__fadd_rn(t01, t23), __fadd_rn(t45, t67));
        }
        Bb[blk] = __fadd_rn(__fadd_rn(L[0], L[1]), __fadd_rn(L[2], L[3]));
      }
    }
    if (isz)
      xxZ[p] = __fadd_rn(__fadd_rn(Bb[0], Bb[1]), __fadd_rn(Bb[2], Bb[3]));
  } else if (gid < 2 * NPIX + Kn) {
    int k = gid - 2 * NPIX;
    cb2[k] = np_pairwise_sq512(CB + (size_t)k * Dn, 1);
  }
}

// ---------------- K1: bf16 MFMA GEMM -> s (bf16 packed into prob slots) ----
// grid 4096; xcd = bid&7, kx = (bid>>3)&7, panel = (bid&7)+8*(bid>>6):
// all 8 kx-blocks of one panel land on ONE XCD within a 64-bid window.
// Tile 128px x 128k, BK=32, double-buffered global_load_lds staging.
// Epilogue: bf16 pack via swizzled LDS tile -> full-line u32 stores.
__global__ __launch_bounds__(256) void k_gemm(const unsigned short* __restrict__ Abf,
                                              const unsigned short* __restrict__ CBbf,
                                              const float* __restrict__ cb2,
                                              float* __restrict__ out) {
  __shared__ __align__(16) unsigned short sE[16384];  // 32 KB: staging, then s-tile
  __shared__ float c2s[128];

  const int bid = blockIdx.x;
  const int kx = (bid >> 3) & 7;
  const int panel = (bid & 7) + 8 * (bid >> 6);   // 0..511
  const int py = panel & 255;
  const int zz = panel >> 8;
  const int p0 = py * 128;
  const int k0 = kx * 128;
  const unsigned short* Asrc = Abf + (size_t)((zz ? NPIX : 0) + p0) * Dn;
  uint32* Sg = (uint32*)(out + (zz ? OFF_PPRB : OFF_PROB));

  const int tid = threadIdx.x;
  const int lane = tid & 63, w = tid >> 6;
  const int fr = lane & 15, fg = lane >> 4;
  const int wm = w & 1, wn = w >> 1;
  if (tid < 128) c2s[tid] = cb2[k0 + tid];

  // staging aliases: At[buf] = sE[buf*4096 ..), Bt[buf] = sE[8192 + buf*4096 ..)
  auto stage = [&](int buf, int c0) {
#pragma unroll
    for (int h = 0; h < 2; h++) {
      const int G = tid + h * 256;
      const int row = G >> 2, g = G & 3;
      const int gsrc = g ^ ((row >> 1) & 3);
      const int ldsbase = ((tid & 192) + h * 256) * 8;  // wave-uniform
      gload_lds16(Asrc + (size_t)row * Dn + c0 + gsrc * 8, &sE[buf * 4096 + ldsbase]);
      gload_lds16(CBbf + (size_t)(k0 + row) * Dn + c0 + gsrc * 8,
                  &sE[8192 + buf * 4096 + ldsbase]);
    }
  };

  stage(0, 0);
  f32x4 acc[4][4] = {};
  const int swz = (fr >> 1) & 3;
#pragma unroll
  for (int s = 0; s < 16; s++) {
    __syncthreads();
    if (s < 15) stage((s + 1) & 1, (s + 1) * 32);
    const int cur = s & 1;
    short8v af[4], bf[4];
#pragma unroll
    for (int m = 0; m < 4; m++)
      af[m] = *(const short8v*)&sE[cur * 4096 + (wm * 64 + m * 16 + fr) * 32 + ((fg ^ swz) * 8)];
#pragma unroll
    for (int n = 0; n < 4; n++)
      bf[n] = *(const short8v*)&sE[8192 + cur * 4096 + (wn * 64 + n * 16 + fr) * 32 + ((fg ^ swz) * 8)];
#pragma unroll
    for (int m = 0; m < 4; m++)
#pragma unroll
      for (int n = 0; n < 4; n++)
        acc[m][n] = __builtin_amdgcn_mfma_f32_16x16x32_bf16(af[m], bf[n], acc[m][n], 0, 0, 0);
  }

  // ---- epilogue: s = cb2 - 2*m -> bf16 -> LDS (granule-XOR) -> full lines ----
  __syncthreads();  // all frag reads done; safe to overwrite staging LDS
#pragma unroll
  for (int n = 0; n < 4; n++) {
    const int kk = wn * 64 + n * 16 + fr;       // k_local 0..127
    const float c2 = c2s[kk];
    const int g = kk >> 3, kb = kk & 7;
#pragma unroll
    for (int m = 0; m < 4; m++) {
#pragma unroll
      for (int r = 0; r < 4; r++) {
        const int px = wm * 64 + m * 16 + fg * 4 + r;
        float sv = __fsub_rn(c2, __fmul_rn(2.0f, acc[m][n][r]));
        sE[px * 128 + ((g ^ (px & 15)) << 3) + kb] = f2bf(sv);
      }
    }
  }
  __syncthreads();
  // store: 16 passes x 8 rows; 32 lanes cover one row's 64 u32 in 2 insts
  const int rr = tid >> 5;      // row-in-pass (0..7)
  const int c32 = tid & 31;     // word slot
#pragma unroll
  for (int pass = 0; pass < 16; pass++) {
    const int px = pass * 8 + rr;
    uint32* dst = Sg + (size_t)(p0 + px) * Kn + kx * 64;
#pragma unroll
    for (int i = 0; i < 2; i++) {
      const int w32 = c32 + 32 * i;            // 0..63
      const int kk2 = w32 * 2;                 // even k_local
      const int g = kk2 >> 3;
      const int byteoff = px * 256 + ((g ^ (px & 15)) << 4) + (kk2 & 7) * 2;
      dst[w32] = *(const uint32*)((const char*)sE + byteoff);
    }
  }
}

// ---------------- K2: per-row: stats + probs + exact refine + loss partial --
// grid (2048, 2), block 256 = 4 waves; wave owns 4 rows. No atomics.
__global__ __launch_bounds__(256) void k_row(const float* __restrict__ Z,
                                             const float* __restrict__ CB,
                                             const float* __restrict__ cb2,
                                             const float* __restrict__ xxZ,
                                             float* __restrict__ out,
                                             int* __restrict__ widx,
                                             float* __restrict__ partial) {
  __shared__ float lsum[4];
  const int zz = blockIdx.y;
  const int p0 = blockIdx.x * 16;
  float* Sbase = out + (zz ? OFF_PPRB : OFF_PROB);
  const int tid = threadIdx.x;
  const int lane = tid & 63, w = tid >> 6;
  float wloss = 0.f;

#pragma unroll 1
  for (int i = 0; i < 4; i++) {
    const int p = p0 + w * 4 + i;
    float* Sp = Sbase + (size_t)p * Kn;
    const uint32* Su = (const uint32*)Sp;
    uint32 uv[8];
#pragma unroll
    for (int q = 0; q < 8; q++) uv[q] = Su[q * 64 + lane];

    float sv[16];
    float v1 = 1e30f, v2 = 1e30f, sum = 0.f;
    int i1 = 0x7fffffff;
#pragma unroll
    for (int q = 0; q < 8; q++) {
      float s0 = bf2f((unsigned short)uv[q]);
      float s1 = bf2f((unsigned short)(uv[q] >> 16));
      sv[2 * q] = s0; sv[2 * q + 1] = s1;
      int k0 = (q * 64 + lane) * 2;
      sum += __expf(-s0) + __expf(-s1);
      if (s0 < v1) { v2 = v1; v1 = s0; i1 = k0; }
      else if (s0 < v2) v2 = s0;
      if (s1 < v1) { v2 = v1; v1 = s1; i1 = k0 + 1; }
      else if (s1 < v2) v2 = s1;
    }
#pragma unroll
    for (int d = 1; d < 64; d <<= 1) {
      float ov1 = __shfl_xor(v1, d, 64);
      int oi1 = __shfl_xor(i1, d, 64);
      float ov2 = __shfl_xor(v2, d, 64);
      float os = __shfl_xor(sum, d, 64);
      sum += os;
      float lose;
      if (ov1 < v1 || (ov1 == v1 && oi1 < i1)) { lose = v1; v1 = ov1; i1 = oi1; }
      else { lose = ov1; }
      v2 = fminf(fminf(v2, ov2), lose);
    }
    const float inv = 1.0f / sum;
    const float thr = v1 + MARGIN;

    // probs (all uv loads consumed by sum-reduce -> safe to overwrite s)
#pragma unroll
    for (int q = 0; q < 8; q++) {
      int k0 = (q * 64 + lane) * 2;
      Sp[k0] = __expf(-sv[2 * q]) * inv;
      Sp[k0 + 1] = __expf(-sv[2 * q + 1]) * inv;
    }

    if (zz == 0) {
      int fin = i1;
      float dfin = v1;
      if (v2 <= thr) {
        // exact f32 refine over in-margin candidates, wave-parallel dot
        const float* zcol = Z + (size_t)(p >> 12) * (Dn * HW) + (p & 4095);
        float zc[8];
#pragma unroll
        for (int q = 0; q < 8; q++) zc[q] = zcol[(size_t)(lane + 64 * q) * HW];
        const float xx = xxZ[p];
        float bd = 1e30f;
        int bi = 0x7fffffff;
#pragma unroll
        for (int q = 0; q < 8; q++) {
#pragma unroll
          for (int hi = 0; hi < 2; hi++) {
            ull mask = __ballot(sv[2 * q + hi] <= thr);
            while (mask) {
              int l = __ffsll(mask) - 1;
              mask &= mask - 1;
              int k = (q * 64 + l) * 2 + hi;
              const float* cr = CB + (size_t)k * Dn;
              float part = 0.f;
#pragma unroll
              for (int q2 = 0; q2 < 8; q2++)
                part = fmaf(zc[q2], cr[lane + 64 * q2], part);
#pragma unroll
              for (int d = 1; d < 64; d <<= 1) part += __shfl_xor(part, d, 64);
              float dd = __fsub_rn(__fadd_rn(xx, cb2[k]), __fmul_rn(2.0f, part));
              if (dd < bd || (dd == bd && k < bi)) { bd = dd; bi = k; }
            }
          }
        }
        fin = bi;
        dfin = bd - xxZ[p];   // bd already includes xx; normalize to s-scale
      }
      wloss += xxZ[p] + dfin;
      if (lane == 0) {
        widx[p] = fin;
        out[OFF_IDX + p] = (float)fin;
      }
    }
  }
  if (zz == 0) {
    if (lane == 0) lsum[w] = wloss;
    __syncthreads();
    if (tid == 0)
      partial[blockIdx.x] = (lsum[0] + lsum[1]) + (lsum[2] + lsum[3]);
  }
}

// ---------------- K3: z_q pure gather (loss comes from k_row) -------------
__global__ __launch_bounds__(256) void k_zq(const float* __restrict__ CB,
                                            const int* __restrict__ widx,
                                            float* __restrict__ out) {
  const int t = threadIdx.x;
  const size_t base = (size_t)blockIdx.x * 4096;
#pragma unroll
  for (int i = 0; i < 16; i++) {
    size_t e = base + (size_t)i * 256 + t;
    int hw = (int)(e & 4095);
    int c = (int)((e >> 12) & 511);
    int bb = (int)(e >> 21);
    int p = (bb << 12) | hw;
    out[e] = CB[(size_t)widx[p] * Dn + c];
  }
}

// ---------------- K4: finalize q_loss from 2048 partials ------------------
__global__ __launch_bounds__(256) void k_loss(const float* __restrict__ partial,
                                              float* __restrict__ out) {
  __shared__ float red[256];
  const int t = threadIdx.x;
  float s = 0.f;
  for (int i = t; i < 2048; i += 256) s += partial[i];
  red[t] = s;
  __syncthreads();
  for (int k = 128; k > 0; k >>= 1) {
    if (t < k) red[t] += red[t + k];
    __syncthreads();
  }
  // q_loss = (1+0.25) * sum_p d_p / (NPIX*Dn)
  if (t == 0) out[OFF_LOSS] = red[0] * (1.25f / 16777216.0f);
}

extern "C" void kernel_launch(void* const* d_in, const int* in_sizes, int n_in,
                              void* d_out, int out_size, void* d_ws, size_t ws_size,
                              hipStream_t stream) {
  const float* Z = (const float*)d_in[0];
  const float* ZP = (const float*)d_in[1];
  const float* CB = (const float*)d_in[2];
  float* out = (float*)d_out;
  char* ws = (char*)d_ws;
  float* cb2 = (float*)(ws + WS_CB2);
  float* xxZ = (float*)(ws + WS_XXZ);
  int* widx = (int*)(ws + WS_WIDX);
  float* partial = (float*)(ws + WS_PART);
  unsigned short* CBbf = (unsigned short*)(ws + WS_CBBF);
  unsigned short* Abf = (ws_size >= WS_ABF + ABF_BYTES)
                            ? (unsigned short*)(ws + WS_ABF)
                            : (unsigned short*)d_out;  // z_q region, rewritten by k_zq

  k_init<<<dim3(1024), 256, 0, stream>>>(Z, ZP, CB, CBbf, Abf, xxZ, cb2);
  k_gemm<<<dim3(4096), 256, 0, stream>>>(Abf, CBbf, cb2, out);
  k_row<<<dim3(2048, 2), 256, 0, stream>>>(Z, CB, cb2, xxZ, out, widx, partial);
  k_zq<<<dim3(4096), 256, 0, stream>>>(CB, widx, out);
  k_loss<<<dim3(1), 256, 0, stream>>>(partial, out);
}

// Round 15
// 419.872 us; speedup vs baseline: 1.9017x; 1.0979x over previous
//
#include <hip/hip_runtime.h>
#include <hip/hip_bf16.h>

static constexpr int Bn = 8, Dn = 512, Hn = 64, Wn = 64, Kn = 1024;
static constexpr int HW = Hn * Wn;            // 4096
static constexpr int NPIX = Bn * HW;          // 32768
static constexpr size_t OFF_LOSS = (size_t)Bn * Dn * HW;          // 16777216
static constexpr size_t OFF_PROB = OFF_LOSS + 1;                   // 16777217
static constexpr size_t OFF_IDX  = OFF_PROB + (size_t)NPIX * Kn;   // 50331649
static constexpr size_t OFF_PPRB = OFF_IDX + NPIX;                 // 50364417

typedef __attribute__((ext_vector_type(8))) short short8v;
typedef __attribute__((ext_vector_type(4))) float f32x4;
typedef unsigned long long ull;
typedef unsigned int uint32;

// workspace layout (bytes)
static constexpr size_t WS_CB2   = 0;         // 1024 f32
static constexpr size_t WS_XXZ   = 4096;      // 32768 f32
static constexpr size_t WS_WIDX  = 135168;    // 32768 i32
static constexpr size_t WS_PART  = 266240;    // 2048 f32
static constexpr size_t WS_CBBF  = 282624;    // 1024*512 bf16 (1 MB)
static constexpr size_t WS_ABF   = 1331200;   // optional 64 MiB A-bf16 scratch
static constexpr size_t ABF_BYTES = (size_t)2 * NPIX * Dn * 2;  // 67108864

#define MARGIN 1e-3f      // f32 refine gate (50-sigma of bf16-GEMM error)
#define CANDSLACK 2.5e-3f // + bf16-s half-ulp slack for candidate enumeration

__device__ inline unsigned short f2bf(float x) {
  unsigned u = __float_as_uint(x);
  u += 0x7fffu + ((u >> 16) & 1u);  // RNE
  return (unsigned short)(u >> 16);
}
__device__ inline unsigned pack2(float a, float b) {
  return (unsigned)f2bf(a) | ((unsigned)f2bf(b) << 16);
}
__device__ inline float bf2f(unsigned short h) {
  return __uint_as_float(((unsigned)h) << 16);
}

__device__ inline void gload_lds16(const void* g, void* l) {
  __builtin_amdgcn_global_load_lds((const __attribute__((address_space(1))) void*)g,
                                   (__attribute__((address_space(3))) void*)l, 16, 0, 0);
}

// ---- numpy pairwise-sum replica for n=512 f32 row of squares ----
__device__ float np_pairwise_sq512(const float* __restrict__ base, int stride) {
  float B[4];
#pragma unroll
  for (int blk = 0; blk < 4; blk++) {
    const float* a = base + (size_t)blk * 128 * stride;
    float r[8][4];
#pragma unroll
    for (int k = 0; k < 8; k++)
#pragma unroll
      for (int j = 0; j < 4; j++) {
        float x = a[(size_t)(4 * k + j) * stride];
        r[k][j] = __fmul_rn(x, x);
      }
#pragma unroll
    for (int i = 32; i < 128; i += 32)
#pragma unroll
      for (int k = 0; k < 8; k++)
#pragma unroll
        for (int j = 0; j < 4; j++) {
          float x = a[(size_t)(i + 4 * k + j) * stride];
          r[k][j] = __fadd_rn(r[k][j], __fmul_rn(x, x));
        }
    float L[4];
#pragma unroll
    for (int j = 0; j < 4; j++) {
      float t01 = __fadd_rn(r[0][j], r[1][j]);
      float t23 = __fadd_rn(r[2][j], r[3][j]);
      float t45 = __fadd_rn(r[4][j], r[5][j]);
      float t67 = __fadd_rn(r[6][j], r[7][j]);
      L[j] = __fadd_rn(__fadd_rn(t01, t23), __fadd_rn(t45, t67));
    }
    B[blk] = __fadd_rn(__fadd_rn(L[0], L[1]), __fadd_rn(L[2], L[3]));
  }
  return __fadd_rn(__fadd_rn(B[0], B[1]), __fadd_rn(B[2], B[3]));
}

// ---------------- K0: CB->bf16, A transpose->bf16 scratch, norms ----------
__global__ __launch_bounds__(256) void k_init(const float* __restrict__ Z,
                                              const float* __restrict__ ZP,
                                              const float* __restrict__ CB,
                                              unsigned short* __restrict__ CBbf,
                                              unsigned short* __restrict__ Abf,
                                              float* __restrict__ xxZ,
                                              float* __restrict__ cb2) {
  int gid = blockIdx.x * 256 + threadIdx.x;
  {
    float2 f = *(const float2*)(CB + (size_t)gid * 2);
    union { __hip_bfloat162 h; unsigned u; } cv;
    cv.h = __float22bfloat162_rn(f);
    ((unsigned*)CBbf)[gid] = cv.u;
  }
  if (gid < 2 * NPIX) {
    const int p = gid & (NPIX - 1);
    const bool isz = gid < NPIX;
    const float* src = (isz ? Z : ZP) + (size_t)(p >> 12) * (Dn * HW) + (p & 4095);
    unsigned short* dst = Abf + (size_t)gid * Dn;
    float Bb[4];
#pragma unroll
    for (int blk = 0; blk < 4; blk++) {
      float rr[32];
#pragma unroll
      for (int i = 0; i < 128; i += 32) {
        float v[32];
#pragma unroll
        for (int t = 0; t < 32; t++) v[t] = src[(size_t)(blk * 128 + i + t) * HW];
        uint4 ua;
        unsigned* uw = (unsigned*)&ua;
#pragma unroll
        for (int q = 0; q < 4; q++) {
#pragma unroll
          for (int e = 0; e < 4; e++) uw[e] = pack2(v[q * 8 + 2 * e], v[q * 8 + 2 * e + 1]);
          *(uint4*)&dst[blk * 128 + i + q * 8] = ua;
        }
        if (isz) {
          if (i == 0) {
#pragma unroll
            for (int t = 0; t < 32; t++) rr[t] = __fmul_rn(v[t], v[t]);
          } else {
#pragma unroll
            for (int t = 0; t < 32; t++) rr[t] = __fadd_rn(rr[t], __fmul_rn(v[t], v[t]));
          }
        }
      }
      if (isz) {
        float L[4];
#pragma unroll
        for (int j = 0; j < 4; j++) {
          float t01 = __fadd_rn(rr[0 + j], rr[4 + j]);
          float t23 = __fadd_rn(rr[8 + j], rr[12 + j]);
          float t45 = __fadd_rn(rr[16 + j], rr[20 + j]);
          float t67 = __fadd_rn(rr[24 + j], rr[28 + j]);
          L[j] = __fadd_rn(__fadd_rn(t01, t23), __fadd_rn(t45, t67));
        }
        Bb[blk] = __fadd_rn(__fadd_rn(L[0], L[1]), __fadd_rn(L[2], L[3]));
      }
    }
    if (isz)
      xxZ[p] = __fadd_rn(__fadd_rn(Bb[0], Bb[1]), __fadd_rn(Bb[2], Bb[3]));
  } else if (gid < 2 * NPIX + Kn) {
    int k = gid - 2 * NPIX;
    cb2[k] = np_pairwise_sq512(CB + (size_t)k * Dn, 1);
  }
}

// ---------------- K1: bf16 MFMA GEMM -> s bf16 + f32 stats sidecar --------
// grid 4096; xcd = bid&7, kx = (bid>>3)&7, panel = (bid&7)+8*(bid>>6).
// s packed to bf16 in the lower 2KB of each prob row; per-row per-kx f32
// (v1,v2,i1) stats stored as float4 in the row's upper 2KB (z rows only) —
// read by k_row before it overwrites the row with probs.
__global__ __launch_bounds__(256) void k_gemm(const unsigned short* __restrict__ Abf,
                                              const unsigned short* __restrict__ CBbf,
                                              const float* __restrict__ cb2,
                                              float* __restrict__ out) {
  __shared__ __align__(16) unsigned short sE[16384];  // 32 KB: staging, then s-tile
  __shared__ float c2s[128];
  __shared__ float rsv[2][128][2];   // [wn][row][v1,v2]
  __shared__ int   rsi[2][128];      // [wn][row] i1 (k_local)

  const int bid = blockIdx.x;
  const int kx = (bid >> 3) & 7;
  const int panel = (bid & 7) + 8 * (bid >> 6);   // 0..511
  const int py = panel & 255;
  const int zz = panel >> 8;
  const int p0 = py * 128;
  const int k0 = kx * 128;
  const unsigned short* Asrc = Abf + (size_t)((zz ? NPIX : 0) + p0) * Dn;
  float* Sf = out + (zz ? OFF_PPRB : OFF_PROB);
  uint32* Sg = (uint32*)Sf;

  const int tid = threadIdx.x;
  const int lane = tid & 63, w = tid >> 6;
  const int fr = lane & 15, fg = lane >> 4;
  const int wm = w & 1, wn = w >> 1;
  if (tid < 128) c2s[tid] = cb2[k0 + tid];

  auto stage = [&](int buf, int c0) {
#pragma unroll
    for (int h = 0; h < 2; h++) {
      const int G = tid + h * 256;
      const int row = G >> 2, g = G & 3;
      const int gsrc = g ^ ((row >> 1) & 3);
      const int ldsbase = ((tid & 192) + h * 256) * 8;  // wave-uniform
      gload_lds16(Asrc + (size_t)row * Dn + c0 + gsrc * 8, &sE[buf * 4096 + ldsbase]);
      gload_lds16(CBbf + (size_t)(k0 + row) * Dn + c0 + gsrc * 8,
                  &sE[8192 + buf * 4096 + ldsbase]);
    }
  };

  stage(0, 0);
  f32x4 acc[4][4] = {};
  const int swz = (fr >> 1) & 3;
#pragma unroll
  for (int s = 0; s < 16; s++) {
    __syncthreads();
    if (s < 15) stage((s + 1) & 1, (s + 1) * 32);
    const int cur = s & 1;
    short8v af[4], bf[4];
#pragma unroll
    for (int m = 0; m < 4; m++)
      af[m] = *(const short8v*)&sE[cur * 4096 + (wm * 64 + m * 16 + fr) * 32 + ((fg ^ swz) * 8)];
#pragma unroll
    for (int n = 0; n < 4; n++)
      bf[n] = *(const short8v*)&sE[8192 + cur * 4096 + (wn * 64 + n * 16 + fr) * 32 + ((fg ^ swz) * 8)];
#pragma unroll
    for (int m = 0; m < 4; m++)
#pragma unroll
      for (int n = 0; n < 4; n++)
        acc[m][n] = __builtin_amdgcn_mfma_f32_16x16x32_bf16(af[m], bf[n], acc[m][n], 0, 0, 0);
  }

  // ---- epilogue: s = cb2 - 2*m -> bf16 pack + per-row f32 (v1,v2,i1) ----
  __syncthreads();  // all frag reads done; safe to overwrite staging LDS
#pragma unroll
  for (int m = 0; m < 4; m++) {
#pragma unroll
    for (int r = 0; r < 4; r++) {
      const int px = wm * 64 + m * 16 + fg * 4 + r;
      float v1 = 1e30f, v2 = 1e30f;
      int i1 = 0x7fffffff;
#pragma unroll
      for (int n = 0; n < 4; n++) {
        const int kk = wn * 64 + n * 16 + fr;
        float sv = __fsub_rn(c2s[kk], __fmul_rn(2.0f, acc[m][n][r]));
        sE[px * 128 + (((kk >> 3) ^ (px & 15)) << 3) + (kk & 7)] = f2bf(sv);
        if (sv < v1) { v2 = v1; v1 = sv; i1 = kk; }
        else if (sv < v2) v2 = sv;
      }
#pragma unroll
      for (int d = 1; d < 16; d <<= 1) {  // lex merge over fr
        float ov1 = __shfl_xor(v1, d, 64);
        int oi1 = __shfl_xor(i1, d, 64);
        float ov2 = __shfl_xor(v2, d, 64);
        float lose;
        if (ov1 < v1 || (ov1 == v1 && oi1 < i1)) { lose = v1; v1 = ov1; i1 = oi1; }
        else lose = ov1;
        v2 = fminf(fminf(v2, ov2), lose);
      }
      if (fr == 0) {
        rsv[wn][px][0] = v1; rsv[wn][px][1] = v2; rsi[wn][px] = i1;
      }
    }
  }
  __syncthreads();

  // stats: merge wn halves, store float4 per row (z rows only)
  if (zz == 0 && tid < 128) {
    float v1 = rsv[0][tid][0], v2 = rsv[0][tid][1];
    int i1 = rsi[0][tid];
    float ov1 = rsv[1][tid][0], ov2 = rsv[1][tid][1];
    int oi1 = rsi[1][tid] + 64;   // wn=1 cols are +64 (i1 stored k_local mod wave)
    // NOTE: rsi holds kk = wn*64 + ..., already global-local; adjust:
    oi1 = rsi[1][tid];            // kk already includes wn*64
    float lose;
    if (ov1 < v1 || (ov1 == v1 && oi1 < i1)) { lose = v1; v1 = ov1; i1 = oi1; }
    else lose = ov1;
    v2 = fminf(fminf(v2, ov2), lose);
    float4 st;
    st.x = v1; st.y = v2; st.z = __int_as_float(k0 + i1); st.w = 0.f;
    *(float4*)(Sf + (size_t)(p0 + tid) * Kn + 512 + kx * 4) = st;
  }

  // s store: full 128B-contiguous lines per row segment
  const int rr = tid >> 5;      // row-in-pass (0..7)
  const int c32 = tid & 31;     // word slot
#pragma unroll
  for (int pass = 0; pass < 16; pass++) {
    const int px = pass * 8 + rr;
    uint32* dst = Sg + (size_t)(p0 + px) * Kn + kx * 64;
#pragma unroll
    for (int i = 0; i < 2; i++) {
      const int w32 = c32 + 32 * i;            // 0..63
      const int kk2 = w32 * 2;                 // even k_local
      const int g = kk2 >> 3;
      const int byteoff = px * 256 + ((g ^ (px & 15)) << 4) + (kk2 & 7) * 2;
      dst[w32] = *(const uint32*)((const char*)sE + byteoff);
    }
  }
}

// ---------------- K2: per-row: sum + probs + stats-gated exact refine ------
// grid (2048, 2), block 256 = 4 waves; wave owns 4 rows. No atomics.
__global__ __launch_bounds__(256) void k_row(const float* __restrict__ Z,
                                             const float* __restrict__ CB,
                                             const float* __restrict__ cb2,
                                             const float* __restrict__ xxZ,
                                             float* __restrict__ out,
                                             int* __restrict__ widx,
                                             float* __restrict__ partial) {
  __shared__ float lsum[4];
  const int zz = blockIdx.y;
  const int p0 = blockIdx.x * 16;
  float* Sbase = out + (zz ? OFF_PPRB : OFF_PROB);
  const int tid = threadIdx.x;
  const int lane = tid & 63, w = tid >> 6;
  float wloss = 0.f;

#pragma unroll 1
  for (int i = 0; i < 4; i++) {
    const int p = p0 + w * 4 + i;
    float* Sp = Sbase + (size_t)p * Kn;
    const uint32* Su = (const uint32*)Sp;
    uint32 uv[8];
#pragma unroll
    for (int q = 0; q < 8; q++) uv[q] = Su[q * 64 + lane];

    float sv[16];
    float sum = 0.f;
#pragma unroll
    for (int q = 0; q < 8; q++) {
      float s0 = bf2f((unsigned short)uv[q]);
      float s1 = bf2f((unsigned short)(uv[q] >> 16));
      sv[2 * q] = s0; sv[2 * q + 1] = s1;
      sum += __expf(-s0) + __expf(-s1);
    }
#pragma unroll
    for (int d = 1; d < 64; d <<= 1) sum += __shfl_xor(sum, d, 64);
    const float inv = 1.0f / sum;

    // exact f32 stats (z only): 8 float4 partials in the row's upper half
    float v1 = 1e30f, v2 = 1e30f;
    int i1 = 0x7fffffff;
    if (zz == 0) {
      if (lane < 8) {
        float4 st = ((const float4*)(Sp + 512))[lane];
        v1 = st.x; v2 = st.y; i1 = __float_as_int(st.z);
      }
#pragma unroll
      for (int d = 1; d < 8; d <<= 1) {  // lex merge over the 8 partials
        float ov1 = __shfl_xor(v1, d, 64);
        int oi1 = __shfl_xor(i1, d, 64);
        float ov2 = __shfl_xor(v2, d, 64);
        float lose;
        if (ov1 < v1 || (ov1 == v1 && oi1 < i1)) { lose = v1; v1 = ov1; i1 = oi1; }
        else lose = ov1;
        v2 = fminf(fminf(v2, ov2), lose);
      }
      v1 = __shfl(v1, 0, 64);
      v2 = __shfl(v2, 0, 64);
      i1 = __shfl(i1, 0, 64);
    }

    // probs (stats already read -> safe to overwrite the row)
#pragma unroll
    for (int q = 0; q < 8; q++) {
      int k0 = (q * 64 + lane) * 2;
      Sp[k0] = __expf(-sv[2 * q]) * inv;
      Sp[k0 + 1] = __expf(-sv[2 * q + 1]) * inv;
    }

    if (zz == 0) {
      int fin = i1;
      float dfin = v1;
      if (v2 <= v1 + MARGIN) {
        // exact f32 refine over in-margin candidates (bf16 enum, widened thr)
        const float thrc = v1 + CANDSLACK;
        const float* zcol = Z + (size_t)(p >> 12) * (Dn * HW) + (p & 4095);
        float zc[8];
#pragma unroll
        for (int q = 0; q < 8; q++) zc[q] = zcol[(size_t)(lane + 64 * q) * HW];
        const float xx = xxZ[p];
        float bd = 1e30f;
        int bi = 0x7fffffff;
#pragma unroll
        for (int q = 0; q < 8; q++) {
#pragma unroll
          for (int hi = 0; hi < 2; hi++) {
            ull mask = __ballot(sv[2 * q + hi] <= thrc);
            while (mask) {
              int l = __ffsll(mask) - 1;
              mask &= mask - 1;
              int k = (q * 64 + l) * 2 + hi;
              const float* cr = CB + (size_t)k * Dn;
              float part = 0.f;
#pragma unroll
              for (int q2 = 0; q2 < 8; q2++)
                part = fmaf(zc[q2], cr[lane + 64 * q2], part);
#pragma unroll
              for (int d = 1; d < 64; d <<= 1) part += __shfl_xor(part, d, 64);
              float dd = __fsub_rn(__fadd_rn(xx, cb2[k]), __fmul_rn(2.0f, part));
              if (dd < bd || (dd == bd && k < bi)) { bd = dd; bi = k; }
            }
          }
        }
        fin = bi;
        dfin = bd - xx;   // normalize back to s-scale
      }
      wloss += xxZ[p] + dfin;
      if (lane == 0) {
        widx[p] = fin;
        out[OFF_IDX + p] = (float)fin;
      }
    }
  }
  if (zz == 0) {
    if (lane == 0) lsum[w] = wloss;
    __syncthreads();
    if (tid == 0)
      partial[blockIdx.x] = (lsum[0] + lsum[1]) + (lsum[2] + lsum[3]);
  }
}

// ---------------- K3: z_q pure gather (loss comes from k_row) -------------
__global__ __launch_bounds__(256) void k_zq(const float* __restrict__ CB,
                                            const int* __restrict__ widx,
                                            float* __restrict__ out) {
  const int t = threadIdx.x;
  const size_t base = (size_t)blockIdx.x * 4096;
#pragma unroll
  for (int i = 0; i < 16; i++) {
    size_t e = base + (size_t)i * 256 + t;
    int hw = (int)(e & 4095);
    int c = (int)((e >> 12) & 511);
    int bb = (int)(e >> 21);
    int p = (bb << 12) | hw;
    out[e] = CB[(size_t)widx[p] * Dn + c];
  }
}

// ---------------- K4: finalize q_loss from 2048 partials ------------------
__global__ __launch_bounds__(256) void k_loss(const float* __restrict__ partial,
                                              float* __restrict__ out) {
  __shared__ float red[256];
  const int t = threadIdx.x;
  float s = 0.f;
  for (int i = t; i < 2048; i += 256) s += partial[i];
  red[t] = s;
  __syncthreads();
  for (int k = 128; k > 0; k >>= 1) {
    if (t < k) red[t] += red[t + k];
    __syncthreads();
  }
  if (t == 0) out[OFF_LOSS] = red[0] * (1.25f / 16777216.0f);
}

extern "C" void kernel_launch(void* const* d_in, const int* in_sizes, int n_in,
                              void* d_out, int out_size, void* d_ws, size_t ws_size,
                              hipStream_t stream) {
  const float* Z = (const float*)d_in[0];
  const float* ZP = (const float*)d_in[1];
  const float* CB = (const float*)d_in[2];
  float* out = (float*)d_out;
  char* ws = (char*)d_ws;
  float* cb2 = (float*)(ws + WS_CB2);
  float* xxZ = (float*)(ws + WS_XXZ);
  int* widx = (int*)(ws + WS_WIDX);
  float* partial = (float*)(ws + WS_PART);
  unsigned short* CBbf = (unsigned short*)(ws + WS_CBBF);
  unsigned short* Abf = (ws_size >= WS_ABF + ABF_BYTES)
                            ? (unsigned short*)(ws + WS_ABF)
                            : (unsigned short*)d_out;  // z_q region, rewritten by k_zq

  k_init<<<dim3(1024), 256, 0, stream>>>(Z, ZP, CB, CBbf, Abf, xxZ, cb2);
  k_gemm<<<dim3(4096), 256, 0, stream>>>(Abf, CBbf, cb2, out);
  k_row<<<dim3(2048, 2), 256, 0, stream>>>(Z, CB, cb2, xxZ, out, widx, partial);
  k_zq<<<dim3(4096), 256, 0, stream>>>(CB, widx, out);
  k_loss<<<dim3(1), 256, 0, stream>>>(partial, out);
}

// Round 16
// 355.086 us; speedup vs baseline: 2.2486x; 1.1825x over previous
//
#include <hip/hip_runtime.h>
#include <hip/hip_bf16.h>

static constexpr int Bn = 8, Dn = 512, Hn = 64, Wn = 64, Kn = 1024;
static constexpr int HW = Hn * Wn;            // 4096
static constexpr int NPIX = Bn * HW;          // 32768
static constexpr size_t OFF_LOSS = (size_t)Bn * Dn * HW;          // 16777216
static constexpr size_t OFF_PROB = OFF_LOSS + 1;                   // 16777217
static constexpr size_t OFF_IDX  = OFF_PROB + (size_t)NPIX * Kn;   // 50331649
static constexpr size_t OFF_PPRB = OFF_IDX + NPIX;                 // 50364417

typedef __attribute__((ext_vector_type(8))) short short8v;
typedef __attribute__((ext_vector_type(4))) float f32x4;
typedef unsigned long long ull;
typedef unsigned int uint32;

// workspace layout (bytes)
static constexpr size_t WS_CB2   = 0;         // 1024 f32
static constexpr size_t WS_XXZ   = 4096;      // 32768 f32
static constexpr size_t WS_WIDX  = 135168;    // 32768 i32
static constexpr size_t WS_PART  = 266240;    // 2048 f32
static constexpr size_t WS_CBBF  = 282624;    // 1024*512 bf16 (1 MB)
static constexpr size_t WS_ABF   = 1331200;   // optional 64 MiB A-bf16 scratch
static constexpr size_t ABF_BYTES = (size_t)2 * NPIX * Dn * 2;  // 67108864

#define MARGIN 1e-3f      // f32 refine gate
#define CANDSLACK 2.5e-3f // + bf16-s half-ulp slack for candidate enumeration

__device__ inline unsigned short f2bf(float x) {
  unsigned u = __float_as_uint(x);
  u += 0x7fffu + ((u >> 16) & 1u);  // RNE
  return (unsigned short)(u >> 16);
}
__device__ inline unsigned pack2(float a, float b) {
  return (unsigned)f2bf(a) | ((unsigned)f2bf(b) << 16);
}
__device__ inline float bf2f(unsigned short h) {
  return __uint_as_float(((unsigned)h) << 16);
}

__device__ inline void gload_lds16(const void* g, void* l) {
  __builtin_amdgcn_global_load_lds((const __attribute__((address_space(1))) void*)g,
                                   (__attribute__((address_space(3))) void*)l, 16, 0, 0);
}

// ---- numpy pairwise-sum replica for n=512 f32 row of squares ----
__device__ float np_pairwise_sq512(const float* __restrict__ base, int stride) {
  float B[4];
#pragma unroll
  for (int blk = 0; blk < 4; blk++) {
    const float* a = base + (size_t)blk * 128 * stride;
    float r[8][4];
#pragma unroll
    for (int k = 0; k < 8; k++)
#pragma unroll
      for (int j = 0; j < 4; j++) {
        float x = a[(size_t)(4 * k + j) * stride];
        r[k][j] = __fmul_rn(x, x);
      }
#pragma unroll
    for (int i = 32; i < 128; i += 32)
#pragma unroll
      for (int k = 0; k < 8; k++)
#pragma unroll
        for (int j = 0; j < 4; j++) {
          float x = a[(size_t)(i + 4 * k + j) * stride];
          r[k][j] = __fadd_rn(r[k][j], __fmul_rn(x, x));
        }
    float L[4];
#pragma unroll
    for (int j = 0; j < 4; j++) {
      float t01 = __fadd_rn(r[0][j], r[1][j]);
      float t23 = __fadd_rn(r[2][j], r[3][j]);
      float t45 = __fadd_rn(r[4][j], r[5][j]);
      float t67 = __fadd_rn(r[6][j], r[7][j]);
      L[j] = __fadd_rn(__fadd_rn(t01, t23), __fadd_rn(t45, t67));
    }
    B[blk] = __fadd_rn(__fadd_rn(L[0], L[1]), __fadd_rn(L[2], L[3]));
  }
  return __fadd_rn(__fadd_rn(B[0], B[1]), __fadd_rn(B[2], B[3]));
}

// ---------------- K0: CB->bf16, A transpose->bf16 scratch, norms ----------
__global__ __launch_bounds__(256) void k_init(const float* __restrict__ Z,
                                              const float* __restrict__ ZP,
                                              const float* __restrict__ CB,
                                              unsigned short* __restrict__ CBbf,
                                              unsigned short* __restrict__ Abf,
                                              float* __restrict__ xxZ,
                                              float* __restrict__ cb2) {
  int gid = blockIdx.x * 256 + threadIdx.x;
  {
    float2 f = *(const float2*)(CB + (size_t)gid * 2);
    union { __hip_bfloat162 h; unsigned u; } cv;
    cv.h = __float22bfloat162_rn(f);
    ((unsigned*)CBbf)[gid] = cv.u;
  }
  if (gid < 2 * NPIX) {
    const int p = gid & (NPIX - 1);
    const bool isz = gid < NPIX;
    const float* src = (isz ? Z : ZP) + (size_t)(p >> 12) * (Dn * HW) + (p & 4095);
    unsigned short* dst = Abf + (size_t)gid * Dn;
    float Bb[4];
#pragma unroll
    for (int blk = 0; blk < 4; blk++) {
      float rr[32];
#pragma unroll
      for (int i = 0; i < 128; i += 32) {
        float v[32];
#pragma unroll
        for (int t = 0; t < 32; t++) v[t] = src[(size_t)(blk * 128 + i + t) * HW];
        uint4 ua;
        unsigned* uw = (unsigned*)&ua;
#pragma unroll
        for (int q = 0; q < 4; q++) {
#pragma unroll
          for (int e = 0; e < 4; e++) uw[e] = pack2(v[q * 8 + 2 * e], v[q * 8 + 2 * e + 1]);
          *(uint4*)&dst[blk * 128 + i + q * 8] = ua;
        }
        if (isz) {
          if (i == 0) {
#pragma unroll
            for (int t = 0; t < 32; t++) rr[t] = __fmul_rn(v[t], v[t]);
          } else {
#pragma unroll
            for (int t = 0; t < 32; t++) rr[t] = __fadd_rn(rr[t], __fmul_rn(v[t], v[t]));
          }
        }
      }
      if (isz) {
        float L[4];
#pragma unroll
        for (int j = 0; j < 4; j++) {
          float t01 = __fadd_rn(rr[0 + j], rr[4 + j]);
          float t23 = __fadd_rn(rr[8 + j], rr[12 + j]);
          float t45 = __fadd_rn(rr[16 + j], rr[20 + j]);
          float t67 = __fadd_rn(rr[24 + j], rr[28 + j]);
          L[j] = __fadd_rn(__fadd_rn(t01, t23), __fadd_rn(t45, t67));
        }
        Bb[blk] = __fadd_rn(__fadd_rn(L[0], L[1]), __fadd_rn(L[2], L[3]));
      }
    }
    if (isz)
      xxZ[p] = __fadd_rn(__fadd_rn(Bb[0], Bb[1]), __fadd_rn(Bb[2], Bb[3]));
  } else if (gid < 2 * NPIX + Kn) {
    int k = gid - 2 * NPIX;
    cb2[k] = np_pairwise_sq512(CB + (size_t)k * Dn, 1);
  }
}

// ---------------- K1: bf16 MFMA GEMM (transposed tiles) -> s bf16 + stats --
// grid 4096; xcd = bid&7, kx = (bid>>3)&7, panel = (bid&7)+8*(bid>>6).
// D[kk][px] = mfma(kf_cb, pf_z): each thread holds 4 CONSECUTIVE kk per
// (m,n) -> 8B LDS packs and cheap row-stats. s bf16 in lower 2KB of each
// prob row; f32 (v1,v2,i1) float4 sidecar in upper 2KB (z rows only).
__global__ __launch_bounds__(256) void k_gemm(const unsigned short* __restrict__ Abf,
                                              const unsigned short* __restrict__ CBbf,
                                              const float* __restrict__ cb2,
                                              float* __restrict__ out) {
  __shared__ __align__(16) unsigned short sE[16384];  // 32 KB: staging, then s-tile
  __shared__ float c2s[128];
  __shared__ float rsv[2][128][2];   // [wm][px][v1,v2]
  __shared__ int   rsi[2][128];      // [wm][px] i1 (kk_local)

  const int bid = blockIdx.x;
  const int kx = (bid >> 3) & 7;
  const int panel = (bid & 7) + 8 * (bid >> 6);   // 0..511
  const int py = panel & 255;
  const int zz = panel >> 8;
  const int p0 = py * 128;
  const int k0 = kx * 128;
  const unsigned short* Asrc = Abf + (size_t)((zz ? NPIX : 0) + p0) * Dn;
  float* Sf = out + (zz ? OFF_PPRB : OFF_PROB);
  uint32* Sg = (uint32*)Sf;

  const int tid = threadIdx.x;
  const int lane = tid & 63, w = tid >> 6;
  const int fr = lane & 15, fg = lane >> 4;
  const int wm = w & 1, wn = w >> 1;   // wm: kk-half, wn: px-half
  if (tid < 128) c2s[tid] = cb2[k0 + tid];

  auto stage = [&](int buf, int c0) {
#pragma unroll
    for (int h = 0; h < 2; h++) {
      const int G = tid + h * 256;
      const int row = G >> 2, g = G & 3;
      const int gsrc = g ^ ((row >> 1) & 3);
      const int ldsbase = ((tid & 192) + h * 256) * 8;  // wave-uniform
      gload_lds16(Asrc + (size_t)row * Dn + c0 + gsrc * 8, &sE[buf * 4096 + ldsbase]);
      gload_lds16(CBbf + (size_t)(k0 + row) * Dn + c0 + gsrc * 8,
                  &sE[8192 + buf * 4096 + ldsbase]);
    }
  };

  stage(0, 0);
  f32x4 acc[4][4] = {};   // [m: kk-16-tile][n: px-16-tile]
  const int swz = (fr >> 1) & 3;
#pragma unroll
  for (int s = 0; s < 16; s++) {
    __syncthreads();
    if (s < 15) stage((s + 1) & 1, (s + 1) * 32);
    const int cur = s & 1;
    short8v kf[4], pf[4];
#pragma unroll
    for (int m = 0; m < 4; m++)   // CB rows (kk)
      kf[m] = *(const short8v*)&sE[8192 + cur * 4096 + (wm * 64 + m * 16 + fr) * 32 + ((fg ^ swz) * 8)];
#pragma unroll
    for (int n = 0; n < 4; n++)   // z rows (px)
      pf[n] = *(const short8v*)&sE[cur * 4096 + (wn * 64 + n * 16 + fr) * 32 + ((fg ^ swz) * 8)];
#pragma unroll
    for (int m = 0; m < 4; m++)
#pragma unroll
      for (int n = 0; n < 4; n++)
        acc[m][n] = __builtin_amdgcn_mfma_f32_16x16x32_bf16(kf[m], pf[n], acc[m][n], 0, 0, 0);
  }

  // ---- epilogue: s(px, kk) = cb2[kk] - 2*D[kk][px]; kk = wm*64+m*16+fg*4+r,
  //      px = wn*64+n*16+fr. 8B packed LDS writes + cheap stats.
  __syncthreads();  // all frag reads done; safe to overwrite staging LDS
  float v1a[4], v2a[4];
  int i1a[4];
#pragma unroll
  for (int n = 0; n < 4; n++) { v1a[n] = 1e30f; v2a[n] = 1e30f; i1a[n] = 0x7fffffff; }
#pragma unroll
  for (int m = 0; m < 4; m++) {
    const int kkb = wm * 64 + m * 16 + fg * 4;
    const float4 c2v = *(const float4*)&c2s[kkb];
#pragma unroll
    for (int n = 0; n < 4; n++) {
      const int px = wn * 64 + n * 16 + fr;
      float s0 = __fsub_rn(c2v.x, __fmul_rn(2.0f, acc[m][n][0]));
      float s1 = __fsub_rn(c2v.y, __fmul_rn(2.0f, acc[m][n][1]));
      float s2 = __fsub_rn(c2v.z, __fmul_rn(2.0f, acc[m][n][2]));
      float s3 = __fsub_rn(c2v.w, __fmul_rn(2.0f, acc[m][n][3]));
      uint2 pk;
      pk.x = pack2(s0, s1);
      pk.y = pack2(s2, s3);
      *(uint2*)((char*)sE + px * 256 + ((kkb * 2) ^ ((px & 15) << 4))) = pk;
      if (s0 < v1a[n]) { v2a[n] = v1a[n]; v1a[n] = s0; i1a[n] = kkb; }
      else if (s0 < v2a[n]) v2a[n] = s0;
      if (s1 < v1a[n]) { v2a[n] = v1a[n]; v1a[n] = s1; i1a[n] = kkb + 1; }
      else if (s1 < v2a[n]) v2a[n] = s1;
      if (s2 < v1a[n]) { v2a[n] = v1a[n]; v1a[n] = s2; i1a[n] = kkb + 2; }
      else if (s2 < v2a[n]) v2a[n] = s2;
      if (s3 < v1a[n]) { v2a[n] = v1a[n]; v1a[n] = s3; i1a[n] = kkb + 3; }
      else if (s3 < v2a[n]) v2a[n] = s3;
    }
  }
  // stats merge over fg (kk interleave): 2 butterfly steps
#pragma unroll
  for (int n = 0; n < 4; n++) {
    float v1 = v1a[n], v2 = v2a[n];
    int i1 = i1a[n];
#pragma unroll
    for (int d = 16; d < 64; d <<= 1) {
      float ov1 = __shfl_xor(v1, d, 64);
      int oi1 = __shfl_xor(i1, d, 64);
      float ov2 = __shfl_xor(v2, d, 64);
      float lose;
      if (ov1 < v1 || (ov1 == v1 && oi1 < i1)) { lose = v1; v1 = ov1; i1 = oi1; }
      else lose = ov1;
      v2 = fminf(fminf(v2, ov2), lose);
    }
    if (fg == 0) {
      const int px = wn * 64 + n * 16 + fr;
      rsv[wm][px][0] = v1; rsv[wm][px][1] = v2; rsi[wm][px] = i1;
    }
  }
  __syncthreads();

  // stats sidecar: merge wm halves, store float4 per row (z rows only)
  if (zz == 0 && tid < 128) {
    float v1 = rsv[0][tid][0], v2 = rsv[0][tid][1];
    int i1 = rsi[0][tid];
    float ov1 = rsv[1][tid][0], ov2 = rsv[1][tid][1];
    int oi1 = rsi[1][tid];       // kk_local already includes wm*64
    float lose;
    if (ov1 < v1 || (ov1 == v1 && oi1 < i1)) { lose = v1; v1 = ov1; i1 = oi1; }
    else lose = ov1;
    v2 = fminf(fminf(v2, ov2), lose);
    float4 st;
    st.x = v1; st.y = v2; st.z = __int_as_float(k0 + i1); st.w = 0.f;
    *(float4*)(Sf + (size_t)(p0 + tid) * Kn + 512 + kx * 4) = st;
  }

  // s store: full 128B-contiguous segments per row
  const int rr = tid >> 5;
  const int c32 = tid & 31;
#pragma unroll
  for (int pass = 0; pass < 16; pass++) {
    const int px = pass * 8 + rr;
    uint32* dst = Sg + (size_t)(p0 + px) * Kn + kx * 64;
#pragma unroll
    for (int i = 0; i < 2; i++) {
      const int w32 = c32 + 32 * i;
      dst[w32] = *(const uint32*)((const char*)sE + px * 256 + ((w32 * 4) ^ ((px & 15) << 4)));
    }
  }
}

// ---------------- K2: per-row: sum + probs + stats-gated exact refine ------
__global__ __launch_bounds__(256) void k_row(const float* __restrict__ Z,
                                             const float* __restrict__ CB,
                                             const float* __restrict__ cb2,
                                             const float* __restrict__ xxZ,
                                             float* __restrict__ out,
                                             int* __restrict__ widx,
                                             float* __restrict__ partial) {
  __shared__ float lsum[4];
  const int zz = blockIdx.y;
  const int p0 = blockIdx.x * 16;
  float* Sbase = out + (zz ? OFF_PPRB : OFF_PROB);
  const int tid = threadIdx.x;
  const int lane = tid & 63, w = tid >> 6;
  float wloss = 0.f;

#pragma unroll 1
  for (int i = 0; i < 4; i++) {
    const int p = p0 + w * 4 + i;
    float* Sp = Sbase + (size_t)p * Kn;
    const uint32* Su = (const uint32*)Sp;
    uint32 uv[8];
#pragma unroll
    for (int q = 0; q < 8; q++) uv[q] = Su[q * 64 + lane];

    float sv[16];
    float sum = 0.f;
#pragma unroll
    for (int q = 0; q < 8; q++) {
      float s0 = bf2f((unsigned short)uv[q]);
      float s1 = bf2f((unsigned short)(uv[q] >> 16));
      sv[2 * q] = s0; sv[2 * q + 1] = s1;
      sum += __expf(-s0) + __expf(-s1);
    }
#pragma unroll
    for (int d = 1; d < 64; d <<= 1) sum += __shfl_xor(sum, d, 64);
    const float inv = 1.0f / sum;

    float v1 = 1e30f, v2 = 1e30f;
    int i1 = 0x7fffffff;
    if (zz == 0) {
      if (lane < 8) {
        float4 st = ((const float4*)(Sp + 512))[lane];
        v1 = st.x; v2 = st.y; i1 = __float_as_int(st.z);
      }
#pragma unroll
      for (int d = 1; d < 8; d <<= 1) {
        float ov1 = __shfl_xor(v1, d, 64);
        int oi1 = __shfl_xor(i1, d, 64);
        float ov2 = __shfl_xor(v2, d, 64);
        float lose;
        if (ov1 < v1 || (ov1 == v1 && oi1 < i1)) { lose = v1; v1 = ov1; i1 = oi1; }
        else lose = ov1;
        v2 = fminf(fminf(v2, ov2), lose);
      }
      v1 = __shfl(v1, 0, 64);
      v2 = __shfl(v2, 0, 64);
      i1 = __shfl(i1, 0, 64);
    }

    // probs (stats already read -> safe to overwrite the row)
#pragma unroll
    for (int q = 0; q < 8; q++) {
      int k0 = (q * 64 + lane) * 2;
      Sp[k0] = __expf(-sv[2 * q]) * inv;
      Sp[k0 + 1] = __expf(-sv[2 * q + 1]) * inv;
    }

    if (zz == 0) {
      int fin = i1;
      float dfin = v1;
      if (v2 <= v1 + MARGIN) {
        const float thrc = v1 + CANDSLACK;
        const float* zcol = Z + (size_t)(p >> 12) * (Dn * HW) + (p & 4095);
        float zc[8];
#pragma unroll
        for (int q = 0; q < 8; q++) zc[q] = zcol[(size_t)(lane + 64 * q) * HW];
        const float xx = xxZ[p];
        float bd = 1e30f;
        int bi = 0x7fffffff;
#pragma unroll
        for (int q = 0; q < 8; q++) {
#pragma unroll
          for (int hi = 0; hi < 2; hi++) {
            ull mask = __ballot(sv[2 * q + hi] <= thrc);
            while (mask) {
              int l = __ffsll(mask) - 1;
              mask &= mask - 1;
              int k = (q * 64 + l) * 2 + hi;
              const float* cr = CB + (size_t)k * Dn;
              float part = 0.f;
#pragma unroll
              for (int q2 = 0; q2 < 8; q2++)
                part = fmaf(zc[q2], cr[lane + 64 * q2], part);
#pragma unroll
              for (int d = 1; d < 64; d <<= 1) part += __shfl_xor(part, d, 64);
              float dd = __fsub_rn(__fadd_rn(xx, cb2[k]), __fmul_rn(2.0f, part));
              if (dd < bd || (dd == bd && k < bi)) { bd = dd; bi = k; }
            }
          }
        }
        fin = bi;
        dfin = bd - xx;
      }
      wloss += xxZ[p] + dfin;
      if (lane == 0) {
        widx[p] = fin;
        out[OFF_IDX + p] = (float)fin;
      }
    }
  }
  if (zz == 0) {
    if (lane == 0) lsum[w] = wloss;
    __syncthreads();
    if (tid == 0)
      partial[blockIdx.x] = (lsum[0] + lsum[1]) + (lsum[2] + lsum[3]);
  }
}

// ---------------- K3: z_q gather via LDS transpose (coalesced both sides) --
// grid 512, block 256. Block: 64 consecutive pixels, all 512 c.
__global__ __launch_bounds__(256) void k_zq(const float* __restrict__ CB,
                                            const int* __restrict__ widx,
                                            float* __restrict__ out) {
  __shared__ float tile[64][65];
  __shared__ int wl[64];
  const int p0 = blockIdx.x * 64;
  const int b = p0 >> 12, hw0 = p0 & 4095;
  const int tid = threadIdx.x;
  if (tid < 64) wl[tid] = widx[p0 + tid];
  __syncthreads();
  const int px = tid >> 2, q = tid & 3;   // reader mapping
  const int px2 = tid & 63, cg = tid >> 6; // writer mapping
  float* obase = out + (size_t)b * (Dn * HW) + hw0;
  for (int c0 = 0; c0 < 512; c0 += 64) {
    const float4* src = (const float4*)(CB + (size_t)wl[px] * Dn + c0 + q * 16);
#pragma unroll
    for (int j = 0; j < 4; j++) {
      float4 v = src[j];
      int c = q * 16 + j * 4;
      tile[c + 0][px] = v.x; tile[c + 1][px] = v.y;
      tile[c + 2][px] = v.z; tile[c + 3][px] = v.w;
    }
    __syncthreads();
#pragma unroll
    for (int pass = 0; pass < 16; pass++) {
      int c = pass * 4 + cg;
      obase[(size_t)(c0 + c) * HW + px2] = tile[c][px2];
    }
    __syncthreads();
  }
}

// ---------------- K4: finalize q_loss from 2048 partials ------------------
__global__ __launch_bounds__(256) void k_loss(const float* __restrict__ partial,
                                              float* __restrict__ out) {
  __shared__ float red[256];
  const int t = threadIdx.x;
  float s = 0.f;
  for (int i = t; i < 2048; i += 256) s += partial[i];
  red[t] = s;
  __syncthreads();
  for (int k = 128; k > 0; k >>= 1) {
    if (t < k) red[t] += red[t + k];
    __syncthreads();
  }
  if (t == 0) out[OFF_LOSS] = red[0] * (1.25f / 16777216.0f);
}

extern "C" void kernel_launch(void* const* d_in, const int* in_sizes, int n_in,
                              void* d_out, int out_size, void* d_ws, size_t ws_size,
                              hipStream_t stream) {
  const float* Z = (const float*)d_in[0];
  const float* ZP = (const float*)d_in[1];
  const float* CB = (const float*)d_in[2];
  float* out = (float*)d_out;
  char* ws = (char*)d_ws;
  float* cb2 = (float*)(ws + WS_CB2);
  float* xxZ = (float*)(ws + WS_XXZ);
  int* widx = (int*)(ws + WS_WIDX);
  float* partial = (float*)(ws + WS_PART);
  unsigned short* CBbf = (unsigned short*)(ws + WS_CBBF);
  unsigned short* Abf = (ws_size >= WS_ABF + ABF_BYTES)
                            ? (unsigned short*)(ws + WS_ABF)
                            : (unsigned short*)d_out;  // z_q region, rewritten by k_zq

  k_init<<<dim3(1024), 256, 0, stream>>>(Z, ZP, CB, CBbf, Abf, xxZ, cb2);
  k_gemm<<<dim3(4096), 256, 0, stream>>>(Abf, CBbf, cb2, out);
  k_row<<<dim3(2048, 2), 256, 0, stream>>>(Z, CB, cb2, xxZ, out, widx, partial);
  k_zq<<<dim3(512), 256, 0, stream>>>(CB, widx, out);
  k_loss<<<dim3(1), 256, 0, stream>>>(partial, out);
}

// Round 18
// 347.872 us; speedup vs baseline: 2.2953x; 1.0207x over previous
//
#include <hip/hip_runtime.h>
#include <hip/hip_bf16.h>

static constexpr int Bn = 8, Dn = 512, Hn = 64, Wn = 64, Kn = 1024;
static constexpr int HW = Hn * Wn;            // 4096
static constexpr int NPIX = Bn * HW;          // 32768
static constexpr size_t OFF_LOSS = (size_t)Bn * Dn * HW;          // 16777216
static constexpr size_t OFF_PROB = OFF_LOSS + 1;                   // 16777217
static constexpr size_t OFF_IDX  = OFF_PROB + (size_t)NPIX * Kn;   // 50331649
static constexpr size_t OFF_PPRB = OFF_IDX + NPIX;                 // 50364417

typedef __attribute__((ext_vector_type(8))) short short8v;
typedef __attribute__((ext_vector_type(4))) float f32x4;
typedef unsigned long long ull;
typedef unsigned int uint32;

// workspace layout (bytes)
static constexpr size_t WS_CB2   = 0;         // 1024 f32
static constexpr size_t WS_XXZ   = 4096;      // 32768 f32
static constexpr size_t WS_WIDX  = 135168;    // 32768 i32
static constexpr size_t WS_PART  = 266240;    // 2048 f32
static constexpr size_t WS_CBBF  = 282624;    // 1024*512 bf16 (1 MB)
static constexpr size_t WS_ABF   = 1331200;   // optional 64 MiB A-bf16 scratch
static constexpr size_t ABF_BYTES = (size_t)2 * NPIX * Dn * 2;  // 67108864

#define MARGIN 1e-3f      // f32 refine gate
#define CANDSLACK 2.5e-3f // + bf16-s half-ulp slack for candidate enumeration

__device__ inline unsigned short f2bf(float x) {
  unsigned u = __float_as_uint(x);
  u += 0x7fffu + ((u >> 16) & 1u);  // RNE
  return (unsigned short)(u >> 16);
}
__device__ inline unsigned pack2(float a, float b) {
  return (unsigned)f2bf(a) | ((unsigned)f2bf(b) << 16);
}
__device__ inline float bf2f(unsigned short h) {
  return __uint_as_float(((unsigned)h) << 16);
}

__device__ inline void gload_lds16(const void* g, void* l) {
  __builtin_amdgcn_global_load_lds((const __attribute__((address_space(1))) void*)g,
                                   (__attribute__((address_space(3))) void*)l, 16, 0, 0);
}

// ---- numpy pairwise-sum replica for n=512 f32 row of squares ----
__device__ float np_pairwise_sq512(const float* __restrict__ base, int stride) {
  float B[4];
#pragma unroll
  for (int blk = 0; blk < 4; blk++) {
    const float* a = base + (size_t)blk * 128 * stride;
    float r[8][4];
#pragma unroll
    for (int k = 0; k < 8; k++)
#pragma unroll
      for (int j = 0; j < 4; j++) {
        float x = a[(size_t)(4 * k + j) * stride];
        r[k][j] = __fmul_rn(x, x);
      }
#pragma unroll
    for (int i = 32; i < 128; i += 32)
#pragma unroll
      for (int k = 0; k < 8; k++)
#pragma unroll
        for (int j = 0; j < 4; j++) {
          float x = a[(size_t)(i + 4 * k + j) * stride];
          r[k][j] = __fadd_rn(r[k][j], __fmul_rn(x, x));
        }
    float L[4];
#pragma unroll
    for (int j = 0; j < 4; j++) {
      float t01 = __fadd_rn(r[0][j], r[1][j]);
      float t23 = __fadd_rn(r[2][j], r[3][j]);
      float t45 = __fadd_rn(r[4][j], r[5][j]);
      float t67 = __fadd_rn(r[6][j], r[7][j]);
      L[j] = __fadd_rn(__fadd_rn(t01, t23), __fadd_rn(t45, t67));
    }
    B[blk] = __fadd_rn(__fadd_rn(L[0], L[1]), __fadd_rn(L[2], L[3]));
  }
  return __fadd_rn(__fadd_rn(B[0], B[1]), __fadd_rn(B[2], B[3]));
}

// ---------------- K0: CB->bf16, A transpose->bf16 scratch, norms ----------
__global__ __launch_bounds__(256) void k_init(const float* __restrict__ Z,
                                              const float* __restrict__ ZP,
                                              const float* __restrict__ CB,
                                              unsigned short* __restrict__ CBbf,
                                              unsigned short* __restrict__ Abf,
                                              float* __restrict__ xxZ,
                                              float* __restrict__ cb2) {
  int gid = blockIdx.x * 256 + threadIdx.x;
  {
    float2 f = *(const float2*)(CB + (size_t)gid * 2);
    union { __hip_bfloat162 h; unsigned u; } cv;
    cv.h = __float22bfloat162_rn(f);
    ((unsigned*)CBbf)[gid] = cv.u;
  }
  if (gid < 2 * NPIX) {
    const int p = gid & (NPIX - 1);
    const bool isz = gid < NPIX;
    const float* src = (isz ? Z : ZP) + (size_t)(p >> 12) * (Dn * HW) + (p & 4095);
    unsigned short* dst = Abf + (size_t)gid * Dn;
    float Bb[4];
#pragma unroll
    for (int blk = 0; blk < 4; blk++) {
      float rr[32];
#pragma unroll
      for (int i = 0; i < 128; i += 32) {
        float v[32];
#pragma unroll
        for (int t = 0; t < 32; t++) v[t] = src[(size_t)(blk * 128 + i + t) * HW];
        uint4 ua;
        unsigned* uw = (unsigned*)&ua;
#pragma unroll
        for (int q = 0; q < 4; q++) {
#pragma unroll
          for (int e = 0; e < 4; e++) uw[e] = pack2(v[q * 8 + 2 * e], v[q * 8 + 2 * e + 1]);
          *(uint4*)&dst[blk * 128 + i + q * 8] = ua;
        }
        if (isz) {
          if (i == 0) {
#pragma unroll
            for (int t = 0; t < 32; t++) rr[t] = __fmul_rn(v[t], v[t]);
          } else {
#pragma unroll
            for (int t = 0; t < 32; t++) rr[t] = __fadd_rn(rr[t], __fmul_rn(v[t], v[t]));
          }
        }
      }
      if (isz) {
        float L[4];
#pragma unroll
        for (int j = 0; j < 4; j++) {
          float t01 = __fadd_rn(rr[0 + j], rr[4 + j]);
          float t23 = __fadd_rn(rr[8 + j], rr[12 + j]);
          float t45 = __fadd_rn(rr[16 + j], rr[20 + j]);
          float t67 = __fadd_rn(rr[24 + j], rr[28 + j]);
          L[j] = __fadd_rn(__fadd_rn(t01, t23), __fadd_rn(t45, t67));
        }
        Bb[blk] = __fadd_rn(__fadd_rn(L[0], L[1]), __fadd_rn(L[2], L[3]));
      }
    }
    if (isz)
      xxZ[p] = __fadd_rn(__fadd_rn(Bb[0], Bb[1]), __fadd_rn(Bb[2], Bb[3]));
  } else if (gid < 2 * NPIX + Kn) {
    int k = gid - 2 * NPIX;
    cb2[k] = np_pairwise_sq512(CB + (size_t)k * Dn, 1);
  }
}

// ---------------- K1: bf16 MFMA GEMM (transposed tiles, 3-buf counted-vmcnt
// pipeline + sched_barrier fences) -> s bf16 + f32 stats sidecar.
// grid 4096; xcd = bid&7, kx = (bid>>3)&7, panel = (bid&7)+8*(bid>>6).
// Raw s_barrier is NOT a compiler memory fence: every s_barrier is followed
// by sched_barrier(0) to pin ds_read/global_load_lds ordering (rule #18).
__global__ __launch_bounds__(256) void k_gemm(const unsigned short* __restrict__ Abf,
                                              const unsigned short* __restrict__ CBbf,
                                              const float* __restrict__ cb2,
                                              float* __restrict__ out) {
  __shared__ __align__(16) unsigned short sE[24576];  // 48 KB: A(b)=b*4096, B(b)=12288+b*4096; pack reuses [0,16384)
  __shared__ float c2s[128];
  __shared__ float rsv[2][128][2];   // [wm][px][v1,v2]
  __shared__ int   rsi[2][128];      // [wm][px] i1 (kk_local)

  const int bid = blockIdx.x;
  const int kx = (bid >> 3) & 7;
  const int panel = (bid & 7) + 8 * (bid >> 6);   // 0..511
  const int py = panel & 255;
  const int zz = panel >> 8;
  const int p0 = py * 128;
  const int k0 = kx * 128;
  const unsigned short* Asrc = Abf + (size_t)((zz ? NPIX : 0) + p0) * Dn;
  float* Sf = out + (zz ? OFF_PPRB : OFF_PROB);
  uint32* Sg = (uint32*)Sf;

  const int tid = threadIdx.x;
  const int lane = tid & 63, w = tid >> 6;
  const int fr = lane & 15, fg = lane >> 4;
  const int wm = w & 1, wn = w >> 1;   // wm: kk-half, wn: px-half
  if (tid < 128) c2s[tid] = cb2[k0 + tid];

  auto stage = [&](int t) {            // t = K-step 0..15, buf = t % 3
    const int buf = t % 3;
    const int c0 = t * 32;
#pragma unroll
    for (int h = 0; h < 2; h++) {
      const int G = tid + h * 256;
      const int row = G >> 2, g = G & 3;
      const int gsrc = g ^ ((row >> 1) & 3);
      const int ldsbase = (tid & 192) * 8 + h * 2048;  // ushort idx, wave-uniform
      gload_lds16(Asrc + (size_t)row * Dn + c0 + gsrc * 8, &sE[buf * 4096 + ldsbase]);
      gload_lds16(CBbf + (size_t)(k0 + row) * Dn + c0 + gsrc * 8,
                  &sE[12288 + buf * 4096 + ldsbase]);
    }
  };

  // prologue: 2 stages in flight, wait only the first
  stage(0);
  stage(1);
  asm volatile("s_waitcnt vmcnt(4)" ::: "memory");
  __builtin_amdgcn_s_barrier();
  __builtin_amdgcn_sched_barrier(0);   // fence: nothing crosses the barrier

  f32x4 acc[4][4] = {};   // [m: kk-16-tile][n: px-16-tile]
  const int swz = (fr >> 1) & 3;
#pragma unroll
  for (int s = 0; s < 16; s++) {
    if (s < 14) stage(s + 2);
    const int buf = s % 3;
    short8v kf[4], pf[4];
#pragma unroll
    for (int m = 0; m < 4; m++)   // CB rows (kk)
      kf[m] = *(const short8v*)&sE[12288 + buf * 4096 + (wm * 64 + m * 16 + fr) * 32 + ((fg ^ swz) * 8)];
#pragma unroll
    for (int n = 0; n < 4; n++)   // z rows (px)
      pf[n] = *(const short8v*)&sE[buf * 4096 + (wn * 64 + n * 16 + fr) * 32 + ((fg ^ swz) * 8)];
#pragma unroll
    for (int m = 0; m < 4; m++)
#pragma unroll
      for (int n = 0; n < 4; n++)
        acc[m][n] = __builtin_amdgcn_mfma_f32_16x16x32_bf16(kf[m], pf[n], acc[m][n], 0, 0, 0);
    if (s < 15) {
      __builtin_amdgcn_sched_barrier(0);  // keep the wait/barrier in place
      if (s < 14) {
        asm volatile("s_waitcnt vmcnt(4)" ::: "memory");  // stage(s+1) done; s+2 in flight
      } else {
        asm volatile("s_waitcnt vmcnt(0)" ::: "memory");  // last stage (15) done
      }
      __builtin_amdgcn_s_barrier();
      __builtin_amdgcn_sched_barrier(0);  // fence: next iter's ds_read/stage stay below
    }
  }

  // ---- epilogue: s(px, kk) = cb2[kk] - 2*D[kk][px]; 8B packed LDS writes ----
  __syncthreads();  // full drain; safe to overwrite staging LDS with pack tile
  float v1a[4], v2a[4];
  int i1a[4];
#pragma unroll
  for (int n = 0; n < 4; n++) { v1a[n] = 1e30f; v2a[n] = 1e30f; i1a[n] = 0x7fffffff; }
#pragma unroll
  for (int m = 0; m < 4; m++) {
    const int kkb = wm * 64 + m * 16 + fg * 4;
    const float4 c2v = *(const float4*)&c2s[kkb];
#pragma unroll
    for (int n = 0; n < 4; n++) {
      const int px = wn * 64 + n * 16 + fr;
      float s0 = __fsub_rn(c2v.x, __fmul_rn(2.0f, acc[m][n][0]));
      float s1 = __fsub_rn(c2v.y, __fmul_rn(2.0f, acc[m][n][1]));
      float s2 = __fsub_rn(c2v.z, __fmul_rn(2.0f, acc[m][n][2]));
      float s3 = __fsub_rn(c2v.w, __fmul_rn(2.0f, acc[m][n][3]));
      uint2 pk;
      pk.x = pack2(s0, s1);
      pk.y = pack2(s2, s3);
      *(uint2*)((char*)sE + px * 256 + ((kkb * 2) ^ ((px & 15) << 4))) = pk;
      if (s0 < v1a[n]) { v2a[n] = v1a[n]; v1a[n] = s0; i1a[n] = kkb; }
      else if (s0 < v2a[n]) v2a[n] = s0;
      if (s1 < v1a[n]) { v2a[n] = v1a[n]; v1a[n] = s1; i1a[n] = kkb + 1; }
      else if (s1 < v2a[n]) v2a[n] = s1;
      if (s2 < v1a[n]) { v2a[n] = v1a[n]; v1a[n] = s2; i1a[n] = kkb + 2; }
      else if (s2 < v2a[n]) v2a[n] = s2;
      if (s3 < v1a[n]) { v2a[n] = v1a[n]; v1a[n] = s3; i1a[n] = kkb + 3; }
      else if (s3 < v2a[n]) v2a[n] = s3;
    }
  }
  // stats merge over fg (kk interleave): 2 butterfly steps
#pragma unroll
  for (int n = 0; n < 4; n++) {
    float v1 = v1a[n], v2 = v2a[n];
    int i1 = i1a[n];
#pragma unroll
    for (int d = 16; d < 64; d <<= 1) {
      float ov1 = __shfl_xor(v1, d, 64);
      int oi1 = __shfl_xor(i1, d, 64);
      float ov2 = __shfl_xor(v2, d, 64);
      float lose;
      if (ov1 < v1 || (ov1 == v1 && oi1 < i1)) { lose = v1; v1 = ov1; i1 = oi1; }
      else lose = ov1;
      v2 = fminf(fminf(v2, ov2), lose);
    }
    if (fg == 0) {
      const int px = wn * 64 + n * 16 + fr;
      rsv[wm][px][0] = v1; rsv[wm][px][1] = v2; rsi[wm][px] = i1;
    }
  }
  __syncthreads();

  // stats sidecar: merge wm halves, store float4 per row (z rows only)
  if (zz == 0 && tid < 128) {
    float v1 = rsv[0][tid][0], v2 = rsv[0][tid][1];
    int i1 = rsi[0][tid];
    float ov1 = rsv[1][tid][0], ov2 = rsv[1][tid][1];
    int oi1 = rsi[1][tid];       // kk_local already includes wm*64
    float lose;
    if (ov1 < v1 || (ov1 == v1 && oi1 < i1)) { lose = v1; v1 = ov1; i1 = oi1; }
    else lose = ov1;
    v2 = fminf(fminf(v2, ov2), lose);
    float4 st;
    st.x = v1; st.y = v2; st.z = __int_as_float(k0 + i1); st.w = 0.f;
    *(float4*)(Sf + (size_t)(p0 + tid) * Kn + 512 + kx * 4) = st;
  }

  // s store: full 128B-contiguous segments per row
  const int rr = tid >> 5;
  const int c32 = tid & 31;
#pragma unroll
  for (int pass = 0; pass < 16; pass++) {
    const int px = pass * 8 + rr;
    uint32* dst = Sg + (size_t)(p0 + px) * Kn + kx * 64;
#pragma unroll
    for (int i = 0; i < 2; i++) {
      const int w32 = c32 + 32 * i;
      dst[w32] = *(const uint32*)((const char*)sE + px * 256 + ((w32 * 4) ^ ((px & 15) << 4)));
    }
  }
}

// ---------------- K2: per-row: sum + probs + stats-gated exact refine ------
__global__ __launch_bounds__(256) void k_row(const float* __restrict__ Z,
                                             const float* __restrict__ CB,
                                             const float* __restrict__ cb2,
                                             const float* __restrict__ xxZ,
                                             float* __restrict__ out,
                                             int* __restrict__ widx,
                                             float* __restrict__ partial) {
  __shared__ float lsum[4];
  const int zz = blockIdx.y;
  const int p0 = blockIdx.x * 16;
  float* Sbase = out + (zz ? OFF_PPRB : OFF_PROB);
  const int tid = threadIdx.x;
  const int lane = tid & 63, w = tid >> 6;
  float wloss = 0.f;

#pragma unroll 1
  for (int i = 0; i < 4; i++) {
    const int p = p0 + w * 4 + i;
    float* Sp = Sbase + (size_t)p * Kn;
    const uint32* Su = (const uint32*)Sp;
    uint32 uv[8];
#pragma unroll
    for (int q = 0; q < 8; q++) uv[q] = Su[q * 64 + lane];

    float sv[16];
    float sum = 0.f;
#pragma unroll
    for (int q = 0; q < 8; q++) {
      float s0 = bf2f((unsigned short)uv[q]);
      float s1 = bf2f((unsigned short)(uv[q] >> 16));
      sv[2 * q] = s0; sv[2 * q + 1] = s1;
      sum += __expf(-s0) + __expf(-s1);
    }
#pragma unroll
    for (int d = 1; d < 64; d <<= 1) sum += __shfl_xor(sum, d, 64);
    const float inv = 1.0f / sum;

    float v1 = 1e30f, v2 = 1e30f;
    int i1 = 0x7fffffff;
    if (zz == 0) {
      if (lane < 8) {
        float4 st = ((const float4*)(Sp + 512))[lane];
        v1 = st.x; v2 = st.y; i1 = __float_as_int(st.z);
      }
#pragma unroll
      for (int d = 1; d < 8; d <<= 1) {
        float ov1 = __shfl_xor(v1, d, 64);
        int oi1 = __shfl_xor(i1, d, 64);
        float ov2 = __shfl_xor(v2, d, 64);
        float lose;
        if (ov1 < v1 || (ov1 == v1 && oi1 < i1)) { lose = v1; v1 = ov1; i1 = oi1; }
        else lose = ov1;
        v2 = fminf(fminf(v2, ov2), lose);
      }
      v1 = __shfl(v1, 0, 64);
      v2 = __shfl(v2, 0, 64);
      i1 = __shfl(i1, 0, 64);
    }

    // probs (stats already read -> safe to overwrite the row)
#pragma unroll
    for (int q = 0; q < 8; q++) {
      int k0 = (q * 64 + lane) * 2;
      Sp[k0] = __expf(-sv[2 * q]) * inv;
      Sp[k0 + 1] = __expf(-sv[2 * q + 1]) * inv;
    }

    if (zz == 0) {
      int fin = i1;
      float dfin = v1;
      if (v2 <= v1 + MARGIN) {
        const float thrc = v1 + CANDSLACK;
        const float* zcol = Z + (size_t)(p >> 12) * (Dn * HW) + (p & 4095);
        float zc[8];
#pragma unroll
        for (int q = 0; q < 8; q++) zc[q] = zcol[(size_t)(lane + 64 * q) * HW];
        const float xx = xxZ[p];
        float bd = 1e30f;
        int bi = 0x7fffffff;
#pragma unroll
        for (int q = 0; q < 8; q++) {
#pragma unroll
          for (int hi = 0; hi < 2; hi++) {
            ull mask = __ballot(sv[2 * q + hi] <= thrc);
            while (mask) {
              int l = __ffsll(mask) - 1;
              mask &= mask - 1;
              int k = (q * 64 + l) * 2 + hi;
              const float* cr = CB + (size_t)k * Dn;
              float part = 0.f;
#pragma unroll
              for (int q2 = 0; q2 < 8; q2++)
                part = fmaf(zc[q2], cr[lane + 64 * q2], part);
#pragma unroll
              for (int d = 1; d < 64; d <<= 1) part += __shfl_xor(part, d, 64);
              float dd = __fsub_rn(__fadd_rn(xx, cb2[k]), __fmul_rn(2.0f, part));
              if (dd < bd || (dd == bd && k < bi)) { bd = dd; bi = k; }
            }
          }
        }
        fin = bi;
        dfin = bd - xx;
      }
      wloss += xxZ[p] + dfin;
      if (lane == 0) {
        widx[p] = fin;
        out[OFF_IDX + p] = (float)fin;
      }
    }
  }
  if (zz == 0) {
    if (lane == 0) lsum[w] = wloss;
    __syncthreads();
    if (tid == 0)
      partial[blockIdx.x] = (lsum[0] + lsum[1]) + (lsum[2] + lsum[3]);
  }
}

// ---------------- K3: z_q gather via LDS transpose (coalesced both sides) --
__global__ __launch_bounds__(256) void k_zq(const float* __restrict__ CB,
                                            const int* __restrict__ widx,
                                            float* __restrict__ out) {
  __shared__ float tile[64][65];
  __shared__ int wl[64];
  const int p0 = blockIdx.x * 64;
  const int b = p0 >> 12, hw0 = p0 & 4095;
  const int tid = threadIdx.x;
  if (tid < 64) wl[tid] = widx[p0 + tid];
  __syncthreads();
  const int px = tid >> 2, q = tid & 3;   // reader mapping
  const int px2 = tid & 63, cg = tid >> 6; // writer mapping
  float* obase = out + (size_t)b * (Dn * HW) + hw0;
  for (int c0 = 0; c0 < 512; c0 += 64) {
    const float4* src = (const float4*)(CB + (size_t)wl[px] * Dn + c0 + q * 16);
#pragma unroll
    for (int j = 0; j < 4; j++) {
      float4 v = src[j];
      int c = q * 16 + j * 4;
      tile[c + 0][px] = v.x; tile[c + 1][px] = v.y;
      tile[c + 2][px] = v.z; tile[c + 3][px] = v.w;
    }
    __syncthreads();
#pragma unroll
    for (int pass = 0; pass < 16; pass++) {
      int c = pass * 4 + cg;
      obase[(size_t)(c0 + c) * HW + px2] = tile[c][px2];
    }
    __syncthreads();
  }
}

// ---------------- K4: finalize q_loss from 2048 partials ------------------
__global__ __launch_bounds__(256) void k_loss(const float* __restrict__ partial,
                                              float* __restrict__ out) {
  __shared__ float red[256];
  const int t = threadIdx.x;
  float s = 0.f;
  for (int i = t; i < 2048; i += 256) s += partial[i];
  red[t] = s;
  __syncthreads();
  for (int k = 128; k > 0; k >>= 1) {
    if (t < k) red[t] += red[t + k];
    __syncthreads();
  }
  if (t == 0) out[OFF_LOSS] = red[0] * (1.25f / 16777216.0f);
}

extern "C" void kernel_launch(void* const* d_in, const int* in_sizes, int n_in,
                              void* d_out, int out_size, void* d_ws, size_t ws_size,
                              hipStream_t stream) {
  const float* Z = (const float*)d_in[0];
  const float* ZP = (const float*)d_in[1];
  const float* CB = (const float*)d_in[2];
  float* out = (float*)d_out;
  char* ws = (char*)d_ws;
  float* cb2 = (float*)(ws + WS_CB2);
  float* xxZ = (float*)(ws + WS_XXZ);
  int* widx = (int*)(ws + WS_WIDX);
  float* partial = (float*)(ws + WS_PART);
  unsigned short* CBbf = (unsigned short*)(ws + WS_CBBF);
  unsigned short* Abf = (ws_size >= WS_ABF + ABF_BYTES)
                            ? (unsigned short*)(ws + WS_ABF)
                            : (unsigned short*)d_out;  // z_q region, rewritten by k_zq

  k_init<<<dim3(1024), 256, 0, stream>>>(Z, ZP, CB, CBbf, Abf, xxZ, cb2);
  k_gemm<<<dim3(4096), 256, 0, stream>>>(Abf, CBbf, cb2, out);
  k_row<<<dim3(2048, 2), 256, 0, stream>>>(Z, CB, cb2, xxZ, out, widx, partial);
  k_zq<<<dim3(512), 256, 0, stream>>>(CB, widx, out);
  k_loss<<<dim3(1), 256, 0, stream>>>(partial, out);
}